// Round 1
// baseline (825.823 us; speedup 1.0000x reference)
//
#include <hip/hip_runtime.h>
#include <hip/hip_bf16.h>
#include <math.h>

typedef __hip_bfloat16 bf16;
typedef __attribute__((ext_vector_type(8))) short short8v;   // 8 bf16 (4 VGPRs)
typedef __attribute__((ext_vector_type(4))) short short4v;   // 4 bf16 (2 VGPRs)
typedef __attribute__((ext_vector_type(4))) float float4v;   // 4 fp32 acc
#define MFMA16 __builtin_amdgcn_mfma_f32_16x16x32_bf16

__device__ __forceinline__ float us2f(unsigned short u) {
  union { unsigned u; float f; } c; c.u = ((unsigned)u) << 16; return c.f;
}
__device__ __forceinline__ unsigned short f2us(float f) {
  return __bfloat16_as_ushort(__float2bfloat16(f));
}

// fp32 x . fp32 w, K % 8 == 0, 16B-aligned
__device__ __forceinline__ float dot_ff(const float* __restrict__ x,
                                        const float* __restrict__ w, int K) {
  const float4* xp = reinterpret_cast<const float4*>(x);
  const float4* wp = reinterpret_cast<const float4*>(w);
  float acc = 0.f;
  const int n = K >> 2;
  for (int i = 0; i < n; ++i) {
    float4 a = xp[i], b = wp[i];
    acc += a.x*b.x + a.y*b.y + a.z*b.z + a.w*b.w;
  }
  return acc;
}

__device__ __forceinline__ float sigm(float x) { return 1.f / (1.f + expf(-x)); }

// ---------------------------------------------------------------------------
__global__ void k_canary(float* __restrict__ out) {
  out[blockIdx.x * 256 + threadIdx.x] = 100.0f;
}

// ---------------------------------------------------------------------------
// One-shot: convert MFMA-consumed weights to bf16 in ws.
// ---------------------------------------------------------------------------
__global__ __launch_bounds__(256) void k_cvt(
    const float* __restrict__ a_in_w, const float* __restrict__ t_in_w,
    const float* __restrict__ t_out_w, const float* __restrict__ t_ff1w,
    const float* __restrict__ t_ff2w,
    unsigned short* __restrict__ awb, unsigned short* __restrict__ twb,
    unsigned short* __restrict__ pwb, unsigned short* __restrict__ f1wb,
    unsigned short* __restrict__ f2wb)
{
  int i = blockIdx.x * 256 + threadIdx.x;
  if (i < 49152)  awb[i] = f2us(a_in_w[i]);
  if (i < 786432) twb[i] = f2us(t_in_w[i]);
  if (i < 262144) pwb[i] = f2us(t_out_w[i]);
  if (i < 524288) f1wb[i] = f2us(t_ff1w[i]);
  if (i < 524288) f2wb[i] = f2us(t_ff2w[i]);
}

// ---------------------------------------------------------------------------
// R11 GRU weight prep: row-major bf16 copies. whhb [dir][768][256],
// wihb [dir][768][128] (for gi GEMM).
// ---------------------------------------------------------------------------
__global__ __launch_bounds__(256) void k_gru_wb(
    const float* __restrict__ wih_f, const float* __restrict__ whh_f,
    const float* __restrict__ wih_b, const float* __restrict__ whh_b,
    unsigned short* __restrict__ whhb, unsigned short* __restrict__ wihb)
{
  int i = blockIdx.x * 256 + threadIdx.x;   // < 393216
  if (i >= 393216) return;
  int dir = i / 196608, r = i % 196608;
  whhb[i] = f2us((dir ? whh_b : whh_f)[r]);
  if (r < 98304) wihb[dir * 98304 + r] = f2us((dir ? wih_b : wih_f)[r]);
}

// ---------------------------------------------------------------------------
// Stage 1: embed + per-order MHA + token-mean + folded out-proj.
// All three matmul phases (QKV, Q.K^T, P.V) on MFMA. Softmax emits
// unnormalized bf16 P (flash-style); 1/sum folded into PV epilogue.
// LDS: ids 128 + xs 8704 (pb overlays) + qk 17408 (o fp32 overlays)
//      + vT 10240 + sc 16896 + om 512 = 53,888 B -> 3 blocks/CU.
// ---------------------------------------------------------------------------
__global__ __launch_bounds__(256, 3) void k_order_attn(
    const int* __restrict__ oh, const float* __restrict__ emb,
    const unsigned short* __restrict__ awb, const float* __restrict__ in_b,
    const float* __restrict__ out_w, const float* __restrict__ out_b,
    float* __restrict__ order_emb)
{
  const int bo = blockIdx.x;            // 0..8191
  const int tid = threadIdx.x;
  __shared__ int ids[32];
  __shared__ alignas(16) unsigned short xs[32 * 136];     // x bf16; P bf16 [128][32] overlays
  __shared__ alignas(16) unsigned short qk[2 * 32 * 136]; // q,k bf16; o fp32 [32][129] overlays
  __shared__ alignas(16) unsigned short vT[128 * 40];     // V^T bf16: vT[d][k]
  __shared__ float sc[128 * 33];                          // scores fp32; col 32 = 1/sum
  __shared__ float om[128];
  unsigned short* qb = qk;
  unsigned short* kb = qk + 32 * 136;
  unsigned short* pb = xs;                                // P overlay (8192 <= 8704)

  const int lane = tid & 63, wave = tid >> 6;
  const int l15 = lane & 15, quad = lane >> 4;

  if (tid < 32) ids[tid] = oh[bo * 32 + tid];
  __syncthreads();
  for (int i = tid; i < 1024; i += 256) {                 // vectorized gather
    int t = i >> 5, d4 = (i & 31) << 2;
    float4 e4 = *reinterpret_cast<const float4*>(emb + (size_t)ids[t] * 128 + d4);
    short4v s; s[0] = f2us(e4.x); s[1] = f2us(e4.y); s[2] = f2us(e4.z); s[3] = f2us(e4.w);
    *reinterpret_cast<short4v*>(xs + t * 136 + d4) = s;
  }
  __syncthreads();
  // ---- QKV MFMA: qkv[t][j] = x[t][.] . w[j][.] ----
  {
    short8v af[2][4];
#pragma unroll
    for (int mt = 0; mt < 2; ++mt)
#pragma unroll
      for (int kc = 0; kc < 4; ++kc)
        af[mt][kc] = *reinterpret_cast<const short8v*>(
            xs + (mt * 16 + l15) * 136 + kc * 32 + quad * 8);
    for (int ni = 0; ni < 6; ++ni) {
      const int j = (wave + ni * 4) * 16 + l15;
      const unsigned short* wrow = awb + (size_t)j * 128;
      float4v acc0 = {0.f, 0.f, 0.f, 0.f}, acc1 = {0.f, 0.f, 0.f, 0.f};
#pragma unroll
      for (int kc = 0; kc < 4; ++kc) {
        short8v bfr = *reinterpret_cast<const short8v*>(wrow + kc * 32 + quad * 8);
        acc0 = MFMA16(af[0][kc], bfr, acc0, 0, 0, 0);
        acc1 = MFMA16(af[1][kc], bfr, acc1, 0, 0, 0);
      }
      const float bj = in_b[j];
      const int jj = j & 127;
      if (j < 256) {
        unsigned short* dst = (j < 128) ? qb : kb;
#pragma unroll
        for (int r = 0; r < 4; ++r) {
          int t0 = quad * 4 + r;
          dst[t0 * 136 + jj] = f2us(acc0[r] + bj);
          dst[(t0 + 16) * 136 + jj] = f2us(acc1[r] + bj);
        }
      } else {                                            // V transposed: vT[d][k]
        short4v s0, s1;
#pragma unroll
        for (int r = 0; r < 4; ++r) { s0[r] = f2us(acc0[r] + bj); s1[r] = f2us(acc1[r] + bj); }
        *reinterpret_cast<short4v*>(vT + jj * 40 + quad * 4) = s0;
        *reinterpret_cast<short4v*>(vT + jj * 40 + 16 + quad * 4) = s1;
      }
    }
  }
  __syncthreads();
  // ---- scores MFMA: wave = head h; S_h = Q_h . K_h^T (M=32,N=32,K=32) ----
  {
    const int h = wave;
    const float scale1 = 0.17677669529663687f;            // 1/sqrt(32)
    short8v qf[2], kf[2];
#pragma unroll
    for (int mt = 0; mt < 2; ++mt)
      qf[mt] = *reinterpret_cast<const short8v*>(qb + (mt * 16 + l15) * 136 + h * 32 + quad * 8);
#pragma unroll
    for (int nt = 0; nt < 2; ++nt)
      kf[nt] = *reinterpret_cast<const short8v*>(kb + (nt * 16 + l15) * 136 + h * 32 + quad * 8);
    float4v acc[2][2];
#pragma unroll
    for (int mt = 0; mt < 2; ++mt)
#pragma unroll
      for (int nt = 0; nt < 2; ++nt) {
        acc[mt][nt] = (float4v){0.f, 0.f, 0.f, 0.f};
        acc[mt][nt] = MFMA16(qf[mt], kf[nt], acc[mt][nt], 0, 0, 0);
      }
#pragma unroll
    for (int mt = 0; mt < 2; ++mt)
#pragma unroll
      for (int nt = 0; nt < 2; ++nt)
#pragma unroll
        for (int r = 0; r < 4; ++r) {
          int q = mt * 16 + quad * 4 + r;
          sc[(h * 32 + q) * 33 + nt * 16 + l15] = acc[mt][nt][r] * scale1;
        }
  }
  __syncthreads();
  // ---- softmax rows: bf16 unnormalized P + 1/sum ----
  if (tid < 128) {
    float* srow = sc + tid * 33;
    float m = srow[0];
#pragma unroll
    for (int c = 1; c < 32; ++c) m = fmaxf(m, srow[c]);
    float s = 0.f;
    unsigned short* prow = pb + tid * 32;
#pragma unroll
    for (int u = 0; u < 4; ++u) {
      short8v pv;
#pragma unroll
      for (int jj2 = 0; jj2 < 8; ++jj2) {
        float e = expf(srow[u * 8 + jj2] - m);
        s += e; pv[jj2] = f2us(e);
      }
      *reinterpret_cast<short8v*>(prow + u * 8) = pv;
    }
    srow[32] = 1.f / s;
  }
  __syncthreads();
  // ---- PV MFMA: wave = head h; O_h = P_h . V_h (M=32,N=32,K=32) ----
  float* o = reinterpret_cast<float*>(qk);                // o[t*129+d] overlays dead q,k
  {
    const int h = wave;
    short8v pf[2], vf[2];
#pragma unroll
    for (int mt = 0; mt < 2; ++mt)
      pf[mt] = *reinterpret_cast<const short8v*>(pb + (h * 32 + mt * 16 + l15) * 32 + quad * 8);
#pragma unroll
    for (int nt = 0; nt < 2; ++nt)
      vf[nt] = *reinterpret_cast<const short8v*>(vT + (h * 32 + nt * 16 + l15) * 40 + quad * 8);
    float4v acc[2][2];
#pragma unroll
    for (int mt = 0; mt < 2; ++mt)
#pragma unroll
      for (int nt = 0; nt < 2; ++nt) {
        acc[mt][nt] = (float4v){0.f, 0.f, 0.f, 0.f};
        acc[mt][nt] = MFMA16(pf[mt], vf[nt], acc[mt][nt], 0, 0, 0);
      }
#pragma unroll
    for (int mt = 0; mt < 2; ++mt)
#pragma unroll
      for (int r = 0; r < 4; ++r) {
        int q = mt * 16 + quad * 4 + r;
        float inv = sc[(h * 32 + q) * 33 + 32];
#pragma unroll
        for (int nt = 0; nt < 2; ++nt)
          o[q * 129 + h * 32 + nt * 16 + l15] = acc[mt][nt][r] * inv;
      }
  }
  __syncthreads();
  if (tid < 128) {
    float acc = 0.f;
#pragma unroll
    for (int t = 0; t < 32; ++t) acc += o[t * 129 + tid];
    om[tid] = acc * (1.f / 32.f);
  }
  __syncthreads();
  if (tid < 128) {
    float acc = dot_ff(om, out_w + (size_t)tid * 128, 128) + out_b[tid];
    order_emb[(size_t)bo * 128 + tid] = acc;
  }
}

// ---------------------------------------------------------------------------
// gi GEMM (MFMA): gi[8192][1536] bf16 = oe @ wih^T (both dirs).
// ---------------------------------------------------------------------------
__global__ __launch_bounds__(256, 2) void k_gru_gi(
    const float* __restrict__ oe, const unsigned short* __restrict__ wihb,
    unsigned short* __restrict__ gi)
{
  const int row0 = blockIdx.x * 32, tid = threadIdx.x;
  __shared__ alignas(16) unsigned short xs[32 * 136];
  for (int i = tid; i < 32 * 128; i += 256) {
    int t = i >> 7, d = i & 127;
    xs[t * 136 + d] = f2us(oe[(size_t)(row0 + t) * 128 + d]);
  }
  __syncthreads();
  const int lane = tid & 63, wave = tid >> 6;
  const int l15 = lane & 15, quad = lane >> 4;
  short8v af[2][4];
#pragma unroll
  for (int mt = 0; mt < 2; ++mt)
#pragma unroll
    for (int kc = 0; kc < 4; ++kc)
      af[mt][kc] = *reinterpret_cast<const short8v*>(
          xs + (mt * 16 + l15) * 136 + kc * 32 + quad * 8);
  for (int ni = 0; ni < 24; ++ni) {
    int col = (wave + ni * 4) * 16 + l15;
    const unsigned short* wrow = wihb + (size_t)col * 128;
    float4v a0 = {0.f,0.f,0.f,0.f}, a1 = {0.f,0.f,0.f,0.f};
#pragma unroll
    for (int kc = 0; kc < 4; ++kc) {
      short8v bfr = *reinterpret_cast<const short8v*>(wrow + kc * 32 + quad * 8);
      a0 = MFMA16(af[0][kc], bfr, a0, 0, 0, 0);
      a1 = MFMA16(af[1][kc], bfr, a1, 0, 0, 0);
    }
#pragma unroll
    for (int r = 0; r < 4; ++r) {
      gi[(size_t)(row0 + quad * 4 + r) * 1536 + col] = f2us(a0[r]);
      gi[(size_t)(row0 + quad * 4 + r + 16) * 1536 + col] = f2us(a1[r]);
    }
  }
}

// ---------------------------------------------------------------------------
// R11 GRU recurrence via MFMA. 16 batches/block (one m-tile), grid (16,2),
// 512 threads (8 waves). whh register-resident: 6 n-tiles/wave x 8 k-chunks
// = 192 VGPRs of B-frags, loaded ONCE. h kept as bf16 in LDS (A operand,
// rewritten by the pointwise phase); matmul out pg fp32 in LDS.
// Per step: 48 MFMA/wave + pointwise; 2 barriers.
// ---------------------------------------------------------------------------
__global__ __launch_bounds__(512, 2) void k_gru_rec(
    const unsigned short* __restrict__ gi, const unsigned short* __restrict__ whhb,
    const float* __restrict__ bih_f, const float* __restrict__ bhh_f,
    const float* __restrict__ bih_b, const float* __restrict__ bhh_b,
    float* __restrict__ g)
{
  const int b0 = blockIdx.x * 16, dir = blockIdx.y;
  const int tid = threadIdx.x;           // 0..511
  const unsigned short* wb = whhb + (size_t)dir * 196608;   // [768][256] bf16
  const float* bih = dir ? bih_b : bih_f;
  const float* bhh = dir ? bhh_b : bhh_f;
  __shared__ alignas(16) unsigned short hb[16 * 264];   // h bf16 (A operand)
  __shared__ float pg[16 * 772];                        // gh fp32
  const int lane = tid & 63, wave = tid >> 6;
  const int l15 = lane & 15, quad = lane >> 4;
  const int j = tid & 255, mb = tid >> 8;               // pointwise: j fixed/thread
  const float bir = bih[j], biz = bih[256 + j], bin_ = bih[512 + j];
  const float bhr = bhh[j], bhz = bhh[256 + j], bhn  = bhh[512 + j];
  // preload whh B-frags (once)
  short8v wf[6][8];
  int cols[6];
#pragma unroll
  for (int ni = 0; ni < 6; ++ni) {
    cols[ni] = (wave + ni * 8) * 16 + l15;
#pragma unroll
    for (int kc = 0; kc < 8; ++kc)
      wf[ni][kc] = *reinterpret_cast<const short8v*>(
          wb + (size_t)cols[ni] * 256 + kc * 32 + quad * 8);
  }
  for (int i = tid; i < 16 * 264; i += 512) hb[i] = 0;
  __syncthreads();
  for (int s = 0; s < 32; ++s) {
    const int t = dir ? (31 - s) : s;
    float4v acc[6];
#pragma unroll
    for (int ni = 0; ni < 6; ++ni) acc[ni] = (float4v){0.f, 0.f, 0.f, 0.f};
#pragma unroll
    for (int kc = 0; kc < 8; ++kc) {
      short8v af = *reinterpret_cast<const short8v*>(hb + l15 * 264 + kc * 32 + quad * 8);
#pragma unroll
      for (int ni = 0; ni < 6; ++ni)
        acc[ni] = MFMA16(af, wf[ni][kc], acc[ni], 0, 0, 0);
    }
#pragma unroll
    for (int ni = 0; ni < 6; ++ni)
#pragma unroll
      for (int r = 0; r < 4; ++r)
        pg[(quad * 4 + r) * 772 + cols[ni]] = acc[ni][r];
    __syncthreads();
#pragma unroll
    for (int it = 0; it < 8; ++it) {
      const int m = mb + 2 * it;
      const size_t gbase = ((size_t)(b0 + m) * 32 + t) * 1536 + dir * 768;
      float gr = us2f(gi[gbase + j]);
      float gz = us2f(gi[gbase + 256 + j]);
      float gn = us2f(gi[gbase + 512 + j]);
      float hprev = us2f(hb[m * 264 + j]);
      float r = sigm(gr + bir + pg[m * 772 + j] + bhr);
      float z = sigm(gz + biz + pg[m * 772 + 256 + j] + bhz);
      float n = tanhf(gn + bin_ + r * (pg[m * 772 + 512 + j] + bhn));
      float nh = (1.f - z) * n + z * hprev;
      hb[m * 264 + j] = f2us(nh);
      g[((size_t)(b0 + m) * 32 + t) * 512 + dir * 256 + j] = nh;
    }
    __syncthreads();
  }
}

// ---------------------------------------------------------------------------
// Stage 3 fused attention, one block per (b, head). QKV, Q.K^T and P.V all
// on MFMA; softmax emits unnormalized bf16 P, 1/sum folded into PV epilogue
// which writes attn directly (no LDS O).
// LDS: xs 33280 (sc+pb overlay) + qk 17408 + vT 10240 = 60,928 B -> 2/CU.
// ---------------------------------------------------------------------------
#define XS_STR 520

__global__ __launch_bounds__(256, 2) void k_mha2f(
    const float* __restrict__ g, const unsigned short* __restrict__ twb,
    const float* __restrict__ Bv, float* __restrict__ attn)
{
  const int b = blockIdx.x, h = blockIdx.y, tid = threadIdx.x;
  __shared__ alignas(16) unsigned short xs[32 * XS_STR];
  __shared__ alignas(16) unsigned short qk[2 * 32 * 136];
  __shared__ alignas(16) unsigned short vT[128 * 40];     // vT[d][k]
  unsigned short* qs = qk;
  unsigned short* ks = qk + 32 * 136;
  float* sc = reinterpret_cast<float*>(xs);               // [32][33] overlay; col 32 = 1/sum
  unsigned short* pb = xs + 2112;                         // P bf16 [32][32] overlay (byte 4224)
  const int lane = tid & 63, wave = tid >> 6;
  const int l15 = lane & 15, quad = lane >> 4;

  for (int i = tid; i < 4096; i += 256) {                 // vectorized x load
    int t = i >> 7, c = (i & 127) << 2;
    float4 e4 = *reinterpret_cast<const float4*>(g + (size_t)b * 16384 + ((size_t)i << 2));
    short4v s; s[0] = f2us(e4.x); s[1] = f2us(e4.y); s[2] = f2us(e4.z); s[3] = f2us(e4.w);
    *reinterpret_cast<short4v*>(xs + t * XS_STR + c) = s;
  }
  __syncthreads();
  // ---- QKV MFMA ----
  {
    int wrowi[6];
#pragma unroll
    for (int ni = 0; ni < 6; ++ni) {
      int idx = (wave + ni * 4) * 16 + l15;
      int m = idx >> 7, dd = idx & 127;
      wrowi[ni] = m * 512 + h * 128 + dd;
    }
    float4v acc[6][2];
#pragma unroll
    for (int ni = 0; ni < 6; ++ni)
#pragma unroll
      for (int mt = 0; mt < 2; ++mt) acc[ni][mt] = (float4v){0.f, 0.f, 0.f, 0.f};
    for (int kc4 = 0; kc4 < 4; ++kc4) {
      short8v af[2][4];
#pragma unroll
      for (int mt = 0; mt < 2; ++mt)
#pragma unroll
        for (int u = 0; u < 4; ++u)
          af[mt][u] = *reinterpret_cast<const short8v*>(
              xs + (mt * 16 + l15) * XS_STR + kc4 * 128 + u * 32 + quad * 8);
#pragma unroll
      for (int ni = 0; ni < 6; ++ni) {
        const unsigned short* wrow = twb + (size_t)wrowi[ni] * 512 + kc4 * 128;
#pragma unroll
        for (int u = 0; u < 4; ++u) {
          short8v bfr = *reinterpret_cast<const short8v*>(wrow + u * 32 + quad * 8);
          acc[ni][0] = MFMA16(af[0][u], bfr, acc[ni][0], 0, 0, 0);
          acc[ni][1] = MFMA16(af[1][u], bfr, acc[ni][1], 0, 0, 0);
        }
      }
    }
#pragma unroll
    for (int ni = 0; ni < 6; ++ni) {
      int idx = (wave + ni * 4) * 16 + l15;
      int m = idx >> 7, dd = idx & 127;
      float bj = Bv[wrowi[ni]];
      if (m < 2) {
        unsigned short* dst = (m == 0) ? qs : ks;
#pragma unroll
        for (int r = 0; r < 4; ++r) {
          int t0 = quad * 4 + r;
          dst[t0 * 136 + dd] = f2us(acc[ni][0][r] + bj);
          dst[(t0 + 16) * 136 + dd] = f2us(acc[ni][1][r] + bj);
        }
      } else {                                            // V transposed: vT[d][k]
        short4v s0, s1;
#pragma unroll
        for (int r = 0; r < 4; ++r) { s0[r] = f2us(acc[ni][0][r] + bj); s1[r] = f2us(acc[ni][1][r] + bj); }
        *reinterpret_cast<short4v*>(vT + dd * 40 + quad * 4) = s0;
        *reinterpret_cast<short4v*>(vT + dd * 40 + 16 + quad * 4) = s1;
      }
    }
  }
  __syncthreads();
  // ---- scores MFMA: wave -> tile (mt,nt); S = Q.K^T (M=32,N=32,K=128) ----
  {
    const float scale2 = 0.08838834764831845f;            // 1/sqrt(128)
    const int mt = wave >> 1, nt = wave & 1;
    float4v acc = {0.f, 0.f, 0.f, 0.f};
#pragma unroll
    for (int kc = 0; kc < 4; ++kc) {
      short8v qf = *reinterpret_cast<const short8v*>(qs + (mt * 16 + l15) * 136 + kc * 32 + quad * 8);
      short8v kf = *reinterpret_cast<const short8v*>(ks + (nt * 16 + l15) * 136 + kc * 32 + quad * 8);
      acc = MFMA16(qf, kf, acc, 0, 0, 0);
    }
#pragma unroll
    for (int r = 0; r < 4; ++r)
      sc[(mt * 16 + quad * 4 + r) * 33 + nt * 16 + l15] = acc[r] * scale2;
  }
  __syncthreads();
  // ---- softmax rows: bf16 unnormalized P + 1/sum ----
  if (tid < 32) {
    float* srow = sc + tid * 33;
    float m = srow[0];
#pragma unroll
    for (int c = 1; c < 32; ++c) m = fmaxf(m, srow[c]);
    float s = 0.f;
    unsigned short* prow = pb + tid * 32;
#pragma unroll
    for (int u = 0; u < 4; ++u) {
      short8v pv;
#pragma unroll
      for (int jj2 = 0; jj2 < 8; ++jj2) {
        float e = expf(srow[u * 8 + jj2] - m);
        s += e; pv[jj2] = f2us(e);
      }
      *reinterpret_cast<short8v*>(prow + u * 8) = pv;
    }
    srow[32] = 1.f / s;
  }
  __syncthreads();
  // ---- PV MFMA: O = P.V (M=32,N=128,K=32); wave handles n-tiles 2w,2w+1 ----
  {
    short8v pf[2], vf[2];
#pragma unroll
    for (int mt = 0; mt < 2; ++mt)
      pf[mt] = *reinterpret_cast<const short8v*>(pb + (mt * 16 + l15) * 32 + quad * 8);
#pragma unroll
    for (int ntl = 0; ntl < 2; ++ntl)
      vf[ntl] = *reinterpret_cast<const short8v*>(vT + ((2 * wave + ntl) * 16 + l15) * 40 + quad * 8);
    float4v acc[2][2];
#pragma unroll
    for (int mt = 0; mt < 2; ++mt)
#pragma unroll
      for (int ntl = 0; ntl < 2; ++ntl) {
        acc[mt][ntl] = (float4v){0.f, 0.f, 0.f, 0.f};
        acc[mt][ntl] = MFMA16(pf[mt], vf[ntl], acc[mt][ntl], 0, 0, 0);
      }
#pragma unroll
    for (int mt = 0; mt < 2; ++mt)
#pragma unroll
      for (int r = 0; r < 4; ++r) {
        int q = mt * 16 + quad * 4 + r;
        float inv = sc[q * 33 + 32];
#pragma unroll
        for (int ntl = 0; ntl < 2; ++ntl)
          attn[((size_t)b * 32 + q) * 512 + h * 128 + (2 * wave + ntl) * 16 + l15] =
              acc[mt][ntl][r] * inv;
      }
  }
}

// ---------------------------------------------------------------------------
// proj GEMM via MFMA (M=16/block, N=512, K=512) + bias + residual + LN.
// ---------------------------------------------------------------------------
__global__ __launch_bounds__(256, 2) void k_projln_mfma(
    const float* __restrict__ X, const unsigned short* __restrict__ Wb,
    const float* __restrict__ bias, const float* __restrict__ res,
    const float* __restrict__ gam, const float* __restrict__ bet,
    float* __restrict__ Y)
{
  const int row0 = blockIdx.x * 16, tid = threadIdx.x;
  __shared__ alignas(16) unsigned short xs[16 * 520];
  __shared__ float ys[16 * 516];
  for (int i = tid; i < 16 * 512; i += 256) {
    int t = i >> 9, c = i & 511;
    xs[t * 520 + c] = f2us(X[(size_t)(row0 + t) * 512 + c]);
  }
  __syncthreads();
  {
    const int lane = tid & 63, wave = tid >> 6;
    const int l15 = lane & 15, quad = lane >> 4;
    short8v af[16];
#pragma unroll
    for (int kc = 0; kc < 16; ++kc)
      af[kc] = *reinterpret_cast<const short8v*>(xs + l15 * 520 + kc * 32 + quad * 8);
    for (int ni = 0; ni < 8; ++ni) {
      int col = (wave + ni * 4) * 16 + l15;
      const unsigned short* wrow = Wb + (size_t)col * 512;
      float4v acc = {0.f,0.f,0.f,0.f};
#pragma unroll
      for (int kc = 0; kc < 16; ++kc) {
        short8v bfr = *reinterpret_cast<const short8v*>(wrow + kc * 32 + quad * 8);
        acc = MFMA16(af[kc], bfr, acc, 0, 0, 0);
      }
      float bj = bias[col];
#pragma unroll
      for (int r = 0; r < 4; ++r)
        ys[(quad * 4 + r) * 516 + col] = acc[r] + bj;
    }
  }
  __syncthreads();
  for (int i = tid; i < 16 * 512; i += 256) {
    int t = i >> 9, c = i & 511;
    ys[t * 516 + c] += res[(size_t)(row0 + t) * 512 + c];
  }
  __syncthreads();
  {
    int row = tid >> 4, l16 = tid & 15;
    const float* yr = ys + row * 516;
    float part = 0.f;
#pragma unroll
    for (int k = 0; k < 32; ++k) part += yr[l16 + 16 * k];
#pragma unroll
    for (int off = 8; off; off >>= 1) part += __shfl_xor(part, off, 16);
    float mean = part * (1.f / 512.f);
    float var = 0.f;
#pragma unroll
    for (int k = 0; k < 32; ++k) { float d = yr[l16 + 16 * k] - mean; var += d * d; }
#pragma unroll
    for (int off = 8; off; off >>= 1) var += __shfl_xor(var, off, 16);
    float rs = rsqrtf(var * (1.f / 512.f) + 1e-5f);
    for (int k = 0; k < 32; ++k) {
      int c = l16 + 16 * k;
      Y[(size_t)(row0 + row) * 512 + c] = (yr[c] - mean) * rs * gam[c] + bet[c];
    }
  }
}

// ---------------------------------------------------------------------------
// ff1 GEMM via MFMA (M=16/block, N=1024, K=512) + bias + relu -> bf16.
// ---------------------------------------------------------------------------
__global__ __launch_bounds__(256, 2) void k_ff1_mfma(
    const float* __restrict__ X, const unsigned short* __restrict__ Wb,
    const float* __restrict__ bias, unsigned short* __restrict__ Y)
{
  const int row0 = blockIdx.x * 16, tid = threadIdx.x;
  __shared__ alignas(16) unsigned short xs[16 * 520];
  for (int i = tid; i < 16 * 512; i += 256) {
    int t = i >> 9, c = i & 511;
    xs[t * 520 + c] = f2us(X[(size_t)(row0 + t) * 512 + c]);
  }
  __syncthreads();
  const int lane = tid & 63, wave = tid >> 6;
  const int l15 = lane & 15, quad = lane >> 4;
  short8v af[16];
#pragma unroll
  for (int kc = 0; kc < 16; ++kc)
    af[kc] = *reinterpret_cast<const short8v*>(xs + l15 * 520 + kc * 32 + quad * 8);
  for (int ni = 0; ni < 16; ++ni) {
    int col = (wave + ni * 4) * 16 + l15;
    const unsigned short* wrow = Wb + (size_t)col * 512;
    float4v acc = {0.f,0.f,0.f,0.f};
#pragma unroll
    for (int kc = 0; kc < 16; ++kc) {
      short8v bfr = *reinterpret_cast<const short8v*>(wrow + kc * 32 + quad * 8);
      acc = MFMA16(af[kc], bfr, acc, 0, 0, 0);
    }
    float bj = bias[col];
#pragma unroll
    for (int r = 0; r < 4; ++r)
      Y[(size_t)(row0 + quad * 4 + r) * 1024 + col] = f2us(fmaxf(acc[r] + bj, 0.f));
  }
}

// ---------------------------------------------------------------------------
// ff2 GEMM via MFMA (M=16/block, N=512, K=1024 in 2 chunks) + bias +
// residual + LN. Y fp32 overlays X bf16 in-place.
// ---------------------------------------------------------------------------
__global__ __launch_bounds__(256, 2) void k_ff2ln_mfma(
    const unsigned short* __restrict__ X, const unsigned short* __restrict__ Wb,
    const float* __restrict__ bias, const float* __restrict__ res,
    const float* __restrict__ gam, const float* __restrict__ bet,
    float* __restrict__ Y)
{
  const int row0 = blockIdx.x * 16, tid = threadIdx.x;
  __shared__ alignas(16) unsigned short xs[16 * 520];
  __shared__ float ys[16 * 516];
  const int lane = tid & 63, wave = tid >> 6;
  const int l15 = lane & 15, quad = lane >> 4;
  float4v acc[8];
#pragma unroll
  for (int ni = 0; ni < 8; ++ni) acc[ni] = (float4v){0.f,0.f,0.f,0.f};
  for (int half = 0; half < 2; ++half) {
    __syncthreads();
    for (int i = tid; i < 16 * 512; i += 256) {
      int t = i >> 9, c = i & 511;
      xs[t * 520 + c] = X[(size_t)(row0 + t) * 1024 + half * 512 + c];
    }
    __syncthreads();
    short8v af[16];
#pragma unroll
    for (int kc = 0; kc < 16; ++kc)
      af[kc] = *reinterpret_cast<const short8v*>(xs + l15 * 520 + kc * 32 + quad * 8);
#pragma unroll
    for (int ni = 0; ni < 8; ++ni) {
      int col = (wave + ni * 4) * 16 + l15;
      const unsigned short* wrow = Wb + (size_t)col * 1024 + half * 512;
#pragma unroll
      for (int kc = 0; kc < 16; ++kc) {
        short8v bfr = *reinterpret_cast<const short8v*>(wrow + kc * 32 + quad * 8);
        acc[ni] = MFMA16(af[kc], bfr, acc[ni], 0, 0, 0);
      }
    }
  }
  __syncthreads();
  for (int ni = 0; ni < 8; ++ni) {
    int col = (wave + ni * 4) * 16 + l15;
    float bj = bias[col];
#pragma unroll
    for (int r = 0; r < 4; ++r)
      ys[(quad * 4 + r) * 516 + col] = acc[ni][r] + bj;
  }
  __syncthreads();
  for (int i = tid; i < 16 * 512; i += 256) {
    int t = i >> 9, c = i & 511;
    ys[t * 516 + c] += res[(size_t)(row0 + t) * 512 + c];
  }
  __syncthreads();
  {
    int row = tid >> 4, l16 = tid & 15;
    const float* yr = ys + row * 516;
    float part = 0.f;
#pragma unroll
    for (int k = 0; k < 32; ++k) part += yr[l16 + 16 * k];
#pragma unroll
    for (int off = 8; off; off >>= 1) part += __shfl_xor(part, off, 16);
    float mean = part * (1.f / 512.f);
    float var = 0.f;
#pragma unroll
    for (int k = 0; k < 32; ++k) { float d = yr[l16 + 16 * k] - mean; var += d * d; }
#pragma unroll
    for (int off = 8; off; off >>= 1) var += __shfl_xor(var, off, 16);
    float rs = rsqrtf(var * (1.f / 512.f) + 1e-5f);
    for (int k = 0; k < 32; ++k) {
      int c = l16 + 16 * k;
      Y[(size_t)(row0 + row) * 512 + c] = (yr[c] - mean) * rs * gam[c] + bet[c];
    }
  }
}

// ---------------------------------------------------------------------------
// Final: mean-pool, temporal MLP, concat, classifier, LN, relu -> fp32
// ---------------------------------------------------------------------------
__global__ __launch_bounds__(256) void k_final(
    const float* __restrict__ g2,
    const float* __restrict__ db, const float* __restrict__ dsl,
    const float* __restrict__ te1_w, const float* __restrict__ te1_b,
    const float* __restrict__ l1g, const float* __restrict__ l1b,
    const float* __restrict__ te2_w, const float* __restrict__ te2_b,
    const float* __restrict__ l2g, const float* __restrict__ l2b,
    const float* __restrict__ c_w, const float* __restrict__ c_b,
    const float* __restrict__ clg, const float* __restrict__ clb,
    float* __restrict__ out)
{
  const int b = blockIdx.x, tid = threadIdx.x;
  __shared__ float cat[640];
  __shared__ float t1[64];
  __shared__ float t2[128];
  __shared__ float pre[256];
  __shared__ float red[256];
  __shared__ float st[2];
  for (int i = tid; i < 512; i += 256) {
    float acc = 0.f;
#pragma unroll
    for (int t = 0; t < 32; ++t) acc += g2[((size_t)b * 32 + t) * 512 + i];
    cat[i] = acc * (1.f / 32.f);
  }
  if (tid == 0) {
    float s = 0.f;
    for (int i = 0; i < 31; ++i) s += db[b * 31 + i];
    st[0] = s / 31.f;
    st[1] = dsl[b];
  }
  __syncthreads();
  const float f0 = st[0], f1v = st[1];
  if (tid < 64)
    t1[tid] = f0 * te1_w[tid * 2] + f1v * te1_w[tid * 2 + 1] + te1_b[tid];
  __syncthreads();
  if (tid == 0) {
    float m = 0.f; for (int i = 0; i < 64; ++i) m += t1[i]; m *= (1.f / 64.f);
    float v = 0.f; for (int i = 0; i < 64; ++i) { float d = t1[i] - m; v += d * d; }
    st[0] = m; st[1] = rsqrtf(v * (1.f / 64.f) + 1e-5f);
  }
  __syncthreads();
  if (tid < 64) {
    float v = (t1[tid] - st[0]) * st[1] * l1g[tid] + l1b[tid];
    t1[tid] = fmaxf(v, 0.f);
  }
  __syncthreads();
  if (tid < 128)
    t2[tid] = dot_ff(t1, te2_w + (size_t)tid * 64, 64) + te2_b[tid];
  __syncthreads();
  if (tid == 0) {
    float m = 0.f; for (int i = 0; i < 128; ++i) m += t2[i]; m *= (1.f / 128.f);
    float v = 0.f; for (int i = 0; i < 128; ++i) { float d = t2[i] - m; v += d * d; }
    st[0] = m; st[1] = rsqrtf(v * (1.f / 128.f) + 1e-5f);
  }
  __syncthreads();
  if (tid < 128) {
    float v = (t2[tid] - st[0]) * st[1] * l2g[tid] + l2b[tid];
    cat[512 + tid] = fmaxf(v, 0.f);
  }
  __syncthreads();
  pre[tid] = dot_ff(cat, c_w + (size_t)tid * 640, 640) + c_b[tid];
  red[tid] = pre[tid];
  __syncthreads();
  for (int s = 128; s > 0; s >>= 1) { if (tid < s) red[tid] += red[tid + s]; __syncthreads(); }
  const float m = red[0] * (1.f / 256.f);
  __syncthreads();
  const float d = pre[tid] - m;
  red[tid] = d * d;
  __syncthreads();
  for (int s = 128; s > 0; s >>= 1) { if (tid < s) red[tid] += red[tid + s]; __syncthreads(); }
  const float rs = rsqrtf(red[0] * (1.f / 256.f) + 1e-5f);
  float v = d * rs * clg[tid] + clb[tid];
  out[(size_t)b * 256 + tid] = fmaxf(v, 0.f);
}

// ---------------------------------------------------------------------------
extern "C" void kernel_launch(void* const* d_in, const int* in_sizes, int n_in,
                              void* d_out, int out_size, void* d_ws, size_t ws_size,
                              hipStream_t stream) {
  (void)in_sizes; (void)n_in; (void)out_size; (void)ws_size;
  const int*   oh     = (const int*)  d_in[0];
  const float* db     = (const float*)d_in[1];
  const float* dsl    = (const float*)d_in[2];
  const float* emb    = (const float*)d_in[3];
  const float* a_in_w = (const float*)d_in[4];
  const float* a_in_b = (const float*)d_in[5];
  const float* a_out_w= (const float*)d_in[6];
  const float* a_out_b= (const float*)d_in[7];
  const float* wih_f  = (const float*)d_in[8];
  const float* whh_f  = (const float*)d_in[9];
  const float* bih_f  = (const float*)d_in[10];
  const float* bhh_f  = (const float*)d_in[11];
  const float* wih_b  = (const float*)d_in[12];
  const float* whh_b  = (const float*)d_in[13];
  const float* bih_b  = (const float*)d_in[14];
  const float* bhh_b  = (const float*)d_in[15];
  const float* t_in_w = (const float*)d_in[16];
  const float* t_in_b = (const float*)d_in[17];
  const float* t_out_w= (const float*)d_in[18];
  const float* t_out_b= (const float*)d_in[19];
  const float* t_ln1g = (const float*)d_in[20];
  const float* t_ln1b = (const float*)d_in[21];
  const float* t_ff1w = (const float*)d_in[22];
  const float* t_ff1b = (const float*)d_in[23];
  const float* t_ff2w = (const float*)d_in[24];
  const float* t_ff2b = (const float*)d_in[25];
  const float* t_ln2g = (const float*)d_in[26];
  const float* t_ln2b = (const float*)d_in[27];
  const float* te1_w  = (const float*)d_in[28];
  const float* te1_b  = (const float*)d_in[29];
  const float* tl1g   = (const float*)d_in[30];
  const float* tl1b   = (const float*)d_in[31];
  const float* te2_w  = (const float*)d_in[32];
  const float* te2_b  = (const float*)d_in[33];
  const float* tl2g   = (const float*)d_in[34];
  const float* tl2b   = (const float*)d_in[35];
  const float* c_w    = (const float*)d_in[36];
  const float* c_b    = (const float*)d_in[37];
  const float* clng   = (const float*)d_in[38];
  const float* clnb   = (const float*)d_in[39];

  float* ws = (float*)d_ws;
  // Workspace (float slots), max index 17,391,616 (~69.6 MB):
  //   A [0,        1048576): oe [8192,128] fp32
  //   B [1048576,  5242880): g fp32 -> f1 bf16 (over dead g) -> g2 fp32
  //   C [5242880,  9437184): attn fp32; g1 = LN out in-place
  //   D [9437184,  9633792): whhb bf16 [2][768][256]
  //   D2[9633792,  9732096): wihb bf16 [2][768][128]
  //   E [10027008,10051584): awb bf16 [384*128]
  //   F [10051584,10444800): twb bf16 [1536*512]
  //   G [10444800,10575872): pwb bf16 [512*512]
  //   G2[10575872,10838016): f1wb bf16 [1024*512]
  //   G3[10838016,11100160): f2wb bf16 [512*1024]
  //   H [11100160,17391616): gi bf16 [8192*1536]
  float* oe   = ws;
  float* g    = ws + 1048576;
  float* attn = ws + 5242880;
  float* g1   = attn;                                   // in-place
  unsigned short* f1 = (unsigned short*)(ws + 1048576); // over dead g
  float* g2   = ws + 1048576;                           // in-place over f1
  unsigned short* whhb = (unsigned short*)(ws + 9437184);
  unsigned short* wihb = (unsigned short*)(ws + 9633792);
  unsigned short* awb  = (unsigned short*)(ws + 10027008);
  unsigned short* twb  = (unsigned short*)(ws + 10051584);
  unsigned short* pwb  = (unsigned short*)(ws + 10444800);
  unsigned short* f1wb = (unsigned short*)(ws + 10575872);
  unsigned short* f2wb = (unsigned short*)(ws + 10838016);
  unsigned short* gi   = (unsigned short*)(ws + 11100160);

  k_canary<<<256, 256, 0, stream>>>((float*)d_out);
  k_cvt<<<3072, 256, 0, stream>>>(a_in_w, t_in_w, t_out_w, t_ff1w, t_ff2w,
                                  awb, twb, pwb, f1wb, f2wb);
  k_gru_wb<<<1536, 256, 0, stream>>>(wih_f, whh_f, wih_b, whh_b, whhb, wihb);
  k_order_attn<<<8192, 256, 0, stream>>>(oh, emb, awb, a_in_b, a_out_w, a_out_b, oe);
  k_gru_gi<<<256, 256, 0, stream>>>(oe, wihb, gi);
  k_gru_rec<<<dim3(16, 2), 512, 0, stream>>>(gi, whhb, bih_f, bhh_f, bih_b, bhh_b, g);
  k_mha2f<<<dim3(256, 4), 256, 0, stream>>>(g, twb, t_in_b, attn);
  k_projln_mfma<<<512, 256, 0, stream>>>(attn, pwb, t_out_b, g, t_ln1g, t_ln1b, g1);
  k_ff1_mfma<<<512, 256, 0, stream>>>(g1, f1wb, t_ff1b, f1);
  k_ff2ln_mfma<<<512, 256, 0, stream>>>(f1, f2wb, t_ff2b, g1, t_ln2g, t_ln2b, g2);
  k_final<<<256, 256, 0, stream>>>(g2, db, dsl, te1_w, te1_b, tl1g, tl1b,
                                   te2_w, te2_b, tl2g, tl2b, c_w, c_b, clng, clnb,
                                   (float*)d_out);
}

// Round 2
// 716.592 us; speedup vs baseline: 1.1524x; 1.1524x over previous
//
#include <hip/hip_runtime.h>
#include <hip/hip_bf16.h>
#include <math.h>

typedef __hip_bfloat16 bf16;
typedef __attribute__((ext_vector_type(8))) short short8v;   // 8 bf16 (4 VGPRs)
typedef __attribute__((ext_vector_type(4))) short short4v;   // 4 bf16 (2 VGPRs)
typedef __attribute__((ext_vector_type(4))) float float4v;   // 4 fp32 acc
#define MFMA16 __builtin_amdgcn_mfma_f32_16x16x32_bf16

__device__ __forceinline__ float us2f(unsigned short u) {
  union { unsigned u; float f; } c; c.u = ((unsigned)u) << 16; return c.f;
}
__device__ __forceinline__ unsigned short f2us(float f) {
  return __bfloat16_as_ushort(__float2bfloat16(f));
}

// fp32 x . fp32 w, K % 8 == 0, 16B-aligned
__device__ __forceinline__ float dot_ff(const float* __restrict__ x,
                                        const float* __restrict__ w, int K) {
  const float4* xp = reinterpret_cast<const float4*>(x);
  const float4* wp = reinterpret_cast<const float4*>(w);
  float acc = 0.f;
  const int n = K >> 2;
  for (int i = 0; i < n; ++i) {
    float4 a = xp[i], b = wp[i];
    acc += a.x*b.x + a.y*b.y + a.z*b.z + a.w*b.w;
  }
  return acc;
}

__device__ __forceinline__ float sigm(float x) { return 1.f / (1.f + expf(-x)); }

// ---------------------------------------------------------------------------
__global__ void k_canary(float* __restrict__ out) {
  out[blockIdx.x * 256 + threadIdx.x] = 100.0f;
}

// ---------------------------------------------------------------------------
// One-shot: convert MFMA-consumed weights to bf16 in ws.
// ---------------------------------------------------------------------------
__global__ __launch_bounds__(256) void k_cvt(
    const float* __restrict__ a_in_w, const float* __restrict__ t_in_w,
    const float* __restrict__ t_out_w, const float* __restrict__ t_ff1w,
    const float* __restrict__ t_ff2w,
    unsigned short* __restrict__ awb, unsigned short* __restrict__ twb,
    unsigned short* __restrict__ pwb, unsigned short* __restrict__ f1wb,
    unsigned short* __restrict__ f2wb)
{
  int i = blockIdx.x * 256 + threadIdx.x;
  if (i < 49152)  awb[i] = f2us(a_in_w[i]);
  if (i < 786432) twb[i] = f2us(t_in_w[i]);
  if (i < 262144) pwb[i] = f2us(t_out_w[i]);
  if (i < 524288) f1wb[i] = f2us(t_ff1w[i]);
  if (i < 524288) f2wb[i] = f2us(t_ff2w[i]);
}

// ---------------------------------------------------------------------------
// R11 GRU weight prep: row-major bf16 copies. whhb [dir][768][256],
// wihb [dir][768][128] (for gi GEMM).
// ---------------------------------------------------------------------------
__global__ __launch_bounds__(256) void k_gru_wb(
    const float* __restrict__ wih_f, const float* __restrict__ whh_f,
    const float* __restrict__ wih_b, const float* __restrict__ whh_b,
    unsigned short* __restrict__ whhb, unsigned short* __restrict__ wihb)
{
  int i = blockIdx.x * 256 + threadIdx.x;   // < 393216
  if (i >= 393216) return;
  int dir = i / 196608, r = i % 196608;
  whhb[i] = f2us((dir ? whh_b : whh_f)[r]);
  if (r < 98304) wihb[dir * 98304 + r] = f2us((dir ? wih_b : wih_f)[r]);
}

// ---------------------------------------------------------------------------
// Stage 1: embed + per-order MHA + token-mean + folded out-proj.
// QKV on MFMA; scores+softmax+PV+token-mean fused into ONE barrier-free
// per-wave phase (wave = head): softmax via shfl_xor row-reduce, inv kept
// in registers, P bf16 (unnormalized) staged in LDS (same-wave read only),
// token-mean via shfl_xor 16/32 over PV accumulators.
// LDS: ids 128 + xs 8704 (P overlays) + qb 8704 + kb 8704 + vT 10240
//      + om 512 + red 1024 = 38,016 B -> 4 blocks/CU.
// ---------------------------------------------------------------------------
__global__ __launch_bounds__(256, 4) void k_order_attn(
    const int* __restrict__ oh, const float* __restrict__ emb,
    const unsigned short* __restrict__ awb, const float* __restrict__ in_b,
    const float* __restrict__ out_w, const float* __restrict__ out_b,
    float* __restrict__ order_emb)
{
  const int bo = blockIdx.x;            // 0..8191
  const int tid = threadIdx.x;
  __shared__ int ids[32];
  __shared__ alignas(16) unsigned short xs[32 * 136];     // x bf16; P [128][32] overlays
  __shared__ alignas(16) unsigned short qb[32 * 136];
  __shared__ alignas(16) unsigned short kb[32 * 136];
  __shared__ alignas(16) unsigned short vT[128 * 40];     // V^T bf16: vT[d][k]
  __shared__ float om[128];
  __shared__ float red[256];
  unsigned short* pb = xs;                                // P overlay (8192 <= 8704)

  const int lane = tid & 63, wave = tid >> 6;
  const int l15 = lane & 15, quad = lane >> 4;

  if (tid < 32) ids[tid] = oh[bo * 32 + tid];
  __syncthreads();
  for (int i = tid; i < 1024; i += 256) {                 // vectorized gather
    int t = i >> 5, d4 = (i & 31) << 2;
    float4 e4 = *reinterpret_cast<const float4*>(emb + (size_t)ids[t] * 128 + d4);
    short4v s; s[0] = f2us(e4.x); s[1] = f2us(e4.y); s[2] = f2us(e4.z); s[3] = f2us(e4.w);
    *reinterpret_cast<short4v*>(xs + t * 136 + d4) = s;
  }
  __syncthreads();
  // ---- QKV MFMA: qkv[t][j] = x[t][.] . w[j][.] ----
  {
    short8v af[2][4];
#pragma unroll
    for (int mt = 0; mt < 2; ++mt)
#pragma unroll
      for (int kc = 0; kc < 4; ++kc)
        af[mt][kc] = *reinterpret_cast<const short8v*>(
            xs + (mt * 16 + l15) * 136 + kc * 32 + quad * 8);
    for (int ni = 0; ni < 6; ++ni) {
      const int j = (wave + ni * 4) * 16 + l15;
      const unsigned short* wrow = awb + (size_t)j * 128;
      float4v acc0 = {0.f, 0.f, 0.f, 0.f}, acc1 = {0.f, 0.f, 0.f, 0.f};
#pragma unroll
      for (int kc = 0; kc < 4; ++kc) {
        short8v bfr = *reinterpret_cast<const short8v*>(wrow + kc * 32 + quad * 8);
        acc0 = MFMA16(af[0][kc], bfr, acc0, 0, 0, 0);
        acc1 = MFMA16(af[1][kc], bfr, acc1, 0, 0, 0);
      }
      const float bj = in_b[j];
      const int jj = j & 127;
      if (j < 256) {
        unsigned short* dst = (j < 128) ? qb : kb;
#pragma unroll
        for (int r = 0; r < 4; ++r) {
          int t0 = quad * 4 + r;
          dst[t0 * 136 + jj] = f2us(acc0[r] + bj);
          dst[(t0 + 16) * 136 + jj] = f2us(acc1[r] + bj);
        }
      } else {                                            // V transposed: vT[d][k]
        short4v s0, s1;
#pragma unroll
        for (int r = 0; r < 4; ++r) { s0[r] = f2us(acc0[r] + bj); s1[r] = f2us(acc1[r] + bj); }
        *reinterpret_cast<short4v*>(vT + jj * 40 + quad * 4) = s0;
        *reinterpret_cast<short4v*>(vT + jj * 40 + 16 + quad * 4) = s1;
      }
    }
  }
  __syncthreads();
  // ---- FUSED: scores + softmax + PV + token-mean (wave = head h) ----
  {
    const int h = wave;
    const float scale1 = 0.17677669529663687f;            // 1/sqrt(32)
    short8v qf[2], kf[2];
#pragma unroll
    for (int mt = 0; mt < 2; ++mt)
      qf[mt] = *reinterpret_cast<const short8v*>(qb + (mt * 16 + l15) * 136 + h * 32 + quad * 8);
#pragma unroll
    for (int nt = 0; nt < 2; ++nt)
      kf[nt] = *reinterpret_cast<const short8v*>(kb + (nt * 16 + l15) * 136 + h * 32 + quad * 8);
    float4v sacc[2][2];
#pragma unroll
    for (int mt = 0; mt < 2; ++mt)
#pragma unroll
      for (int nt = 0; nt < 2; ++nt) {
        sacc[mt][nt] = (float4v){0.f, 0.f, 0.f, 0.f};
        sacc[mt][nt] = MFMA16(qf[mt], kf[nt], sacc[mt][nt], 0, 0, 0);
      }
    // softmax per row (row elements live across the 16 lanes of one quad, x2 nt)
    float inv_reg[2][4];
#pragma unroll
    for (int mt = 0; mt < 2; ++mt)
#pragma unroll
      for (int r = 0; r < 4; ++r) {
        float s0 = sacc[mt][0][r] * scale1;
        float s1 = sacc[mt][1][r] * scale1;
        float mx = fmaxf(s0, s1);
        mx = fmaxf(mx, __shfl_xor(mx, 1));
        mx = fmaxf(mx, __shfl_xor(mx, 2));
        mx = fmaxf(mx, __shfl_xor(mx, 4));
        mx = fmaxf(mx, __shfl_xor(mx, 8));
        float e0 = expf(s0 - mx), e1 = expf(s1 - mx);
        float sm = e0 + e1;
        sm += __shfl_xor(sm, 1);
        sm += __shfl_xor(sm, 2);
        sm += __shfl_xor(sm, 4);
        sm += __shfl_xor(sm, 8);
        inv_reg[mt][r] = 1.f / sm;
        int row = h * 32 + mt * 16 + quad * 4 + r;
        pb[row * 32 + l15] = f2us(e0);
        pb[row * 32 + 16 + l15] = f2us(e1);
      }
    // PV (reads only this wave's P rows -> no barrier needed)
    short8v pf[2], vf[2];
#pragma unroll
    for (int mt = 0; mt < 2; ++mt)
      pf[mt] = *reinterpret_cast<const short8v*>(pb + (h * 32 + mt * 16 + l15) * 32 + quad * 8);
#pragma unroll
    for (int nt = 0; nt < 2; ++nt)
      vf[nt] = *reinterpret_cast<const short8v*>(vT + (h * 32 + nt * 16 + l15) * 40 + quad * 8);
    float4v oacc[2][2];
#pragma unroll
    for (int mt = 0; mt < 2; ++mt)
#pragma unroll
      for (int nt = 0; nt < 2; ++nt) {
        oacc[mt][nt] = (float4v){0.f, 0.f, 0.f, 0.f};
        oacc[mt][nt] = MFMA16(pf[mt], vf[nt], oacc[mt][nt], 0, 0, 0);
      }
    // token-mean via in-lane + cross-quad reduce
    float part0 = 0.f, part1 = 0.f;
#pragma unroll
    for (int mt = 0; mt < 2; ++mt)
#pragma unroll
      for (int r = 0; r < 4; ++r) {
        part0 += oacc[mt][0][r] * inv_reg[mt][r];
        part1 += oacc[mt][1][r] * inv_reg[mt][r];
      }
    part0 += __shfl_xor(part0, 16); part0 += __shfl_xor(part0, 32);
    part1 += __shfl_xor(part1, 16); part1 += __shfl_xor(part1, 32);
    if (quad == 0) {
      om[h * 32 + l15] = part0 * (1.f / 32.f);
      om[h * 32 + 16 + l15] = part1 * (1.f / 32.f);
    }
  }
  __syncthreads();
  // ---- out-proj: 2 threads per output dim (K=64 halves) ----
  {
    int d = tid & 127, half = tid >> 7;
    red[tid] = dot_ff(om + half * 64, out_w + (size_t)d * 128 + half * 64, 64);
  }
  __syncthreads();
  if (tid < 128)
    order_emb[(size_t)bo * 128 + tid] = red[tid] + red[tid + 128] + out_b[tid];
}

// ---------------------------------------------------------------------------
// gi GEMM (MFMA): gi[8192][1536] bf16 = oe @ wih^T (both dirs).
// ---------------------------------------------------------------------------
__global__ __launch_bounds__(256, 2) void k_gru_gi(
    const float* __restrict__ oe, const unsigned short* __restrict__ wihb,
    unsigned short* __restrict__ gi)
{
  const int row0 = blockIdx.x * 32, tid = threadIdx.x;
  __shared__ alignas(16) unsigned short xs[32 * 136];
  for (int i = tid; i < 32 * 128; i += 256) {
    int t = i >> 7, d = i & 127;
    xs[t * 136 + d] = f2us(oe[(size_t)(row0 + t) * 128 + d]);
  }
  __syncthreads();
  const int lane = tid & 63, wave = tid >> 6;
  const int l15 = lane & 15, quad = lane >> 4;
  short8v af[2][4];
#pragma unroll
  for (int mt = 0; mt < 2; ++mt)
#pragma unroll
    for (int kc = 0; kc < 4; ++kc)
      af[mt][kc] = *reinterpret_cast<const short8v*>(
          xs + (mt * 16 + l15) * 136 + kc * 32 + quad * 8);
  for (int ni = 0; ni < 24; ++ni) {
    int col = (wave + ni * 4) * 16 + l15;
    const unsigned short* wrow = wihb + (size_t)col * 128;
    float4v a0 = {0.f,0.f,0.f,0.f}, a1 = {0.f,0.f,0.f,0.f};
#pragma unroll
    for (int kc = 0; kc < 4; ++kc) {
      short8v bfr = *reinterpret_cast<const short8v*>(wrow + kc * 32 + quad * 8);
      a0 = MFMA16(af[0][kc], bfr, a0, 0, 0, 0);
      a1 = MFMA16(af[1][kc], bfr, a1, 0, 0, 0);
    }
#pragma unroll
    for (int r = 0; r < 4; ++r) {
      gi[(size_t)(row0 + quad * 4 + r) * 1536 + col] = f2us(a0[r]);
      gi[(size_t)(row0 + quad * 4 + r + 16) * 1536 + col] = f2us(a1[r]);
    }
  }
}

// ---------------------------------------------------------------------------
// R11 GRU recurrence via MFMA. 8 batches/block, grid (32,2), 512 threads
// (8 waves). MFMA M=16 rows; rows 8-15 stay zero (harmless). whh
// register-resident: 6 n-tiles/wave x 8 k-chunks, loaded ONCE. h bf16 in
// LDS; matmul out pg fp32 in LDS. Per step: 48 MFMA/wave + pointwise.
// ---------------------------------------------------------------------------
__global__ __launch_bounds__(512, 2) void k_gru_rec(
    const unsigned short* __restrict__ gi, const unsigned short* __restrict__ whhb,
    const float* __restrict__ bih_f, const float* __restrict__ bhh_f,
    const float* __restrict__ bih_b, const float* __restrict__ bhh_b,
    float* __restrict__ g)
{
  const int b0 = blockIdx.x * 8, dir = blockIdx.y;
  const int tid = threadIdx.x;           // 0..511
  const unsigned short* wb = whhb + (size_t)dir * 196608;   // [768][256] bf16
  const float* bih = dir ? bih_b : bih_f;
  const float* bhh = dir ? bhh_b : bhh_f;
  __shared__ alignas(16) unsigned short hb[16 * 264];   // h bf16 (A operand)
  __shared__ float pg[16 * 772];                        // gh fp32
  const int lane = tid & 63, wave = tid >> 6;
  const int l15 = lane & 15, quad = lane >> 4;
  const int j = tid & 255, mb = tid >> 8;               // pointwise: j fixed/thread
  const float bir = bih[j], biz = bih[256 + j], bin_ = bih[512 + j];
  const float bhr = bhh[j], bhz = bhh[256 + j], bhn  = bhh[512 + j];
  // preload whh B-frags (once)
  short8v wf[6][8];
  int cols[6];
#pragma unroll
  for (int ni = 0; ni < 6; ++ni) {
    cols[ni] = (wave + ni * 8) * 16 + l15;
#pragma unroll
    for (int kc = 0; kc < 8; ++kc)
      wf[ni][kc] = *reinterpret_cast<const short8v*>(
          wb + (size_t)cols[ni] * 256 + kc * 32 + quad * 8);
  }
  for (int i = tid; i < 16 * 264; i += 512) hb[i] = 0;
  __syncthreads();
  for (int s = 0; s < 32; ++s) {
    const int t = dir ? (31 - s) : s;
    float4v acc[6];
#pragma unroll
    for (int ni = 0; ni < 6; ++ni) acc[ni] = (float4v){0.f, 0.f, 0.f, 0.f};
#pragma unroll
    for (int kc = 0; kc < 8; ++kc) {
      short8v af = *reinterpret_cast<const short8v*>(hb + l15 * 264 + kc * 32 + quad * 8);
#pragma unroll
      for (int ni = 0; ni < 6; ++ni)
        acc[ni] = MFMA16(af, wf[ni][kc], acc[ni], 0, 0, 0);
    }
#pragma unroll
    for (int ni = 0; ni < 6; ++ni)
#pragma unroll
      for (int r = 0; r < 4; ++r)
        pg[(quad * 4 + r) * 772 + cols[ni]] = acc[ni][r];
    __syncthreads();
#pragma unroll
    for (int it = 0; it < 4; ++it) {
      const int m = mb + 2 * it;
      const size_t gbase = ((size_t)(b0 + m) * 32 + t) * 1536 + dir * 768;
      float gr = us2f(gi[gbase + j]);
      float gz = us2f(gi[gbase + 256 + j]);
      float gn = us2f(gi[gbase + 512 + j]);
      float hprev = us2f(hb[m * 264 + j]);
      float r = sigm(gr + bir + pg[m * 772 + j] + bhr);
      float z = sigm(gz + biz + pg[m * 772 + 256 + j] + bhz);
      float n = tanhf(gn + bin_ + r * (pg[m * 772 + 512 + j] + bhn));
      float nh = (1.f - z) * n + z * hprev;
      hb[m * 264 + j] = f2us(nh);
      g[((size_t)(b0 + m) * 32 + t) * 512 + dir * 256 + j] = nh;
    }
    __syncthreads();
  }
}

// ---------------------------------------------------------------------------
// Stage 3 fused attention, one block per (b, head). QKV, Q.K^T and P.V all
// on MFMA; softmax (128 threads, 4 lanes/row, shfl-reduce) emits
// unnormalized bf16 P, 1/sum folded into PV epilogue which writes attn.
// LDS: xs 33280 (sc+pb overlay) + qk 17408 + vT 10240 = 60,928 -> 2/CU.
// ---------------------------------------------------------------------------
#define XS_STR 520

__global__ __launch_bounds__(256, 2) void k_mha2f(
    const float* __restrict__ g, const unsigned short* __restrict__ twb,
    const float* __restrict__ Bv, float* __restrict__ attn)
{
  const int b = blockIdx.x, h = blockIdx.y, tid = threadIdx.x;
  __shared__ alignas(16) unsigned short xs[32 * XS_STR];
  __shared__ alignas(16) unsigned short qk[2 * 32 * 136];
  __shared__ alignas(16) unsigned short vT[128 * 40];     // vT[d][k]
  unsigned short* qs = qk;
  unsigned short* ks = qk + 32 * 136;
  float* sc = reinterpret_cast<float*>(xs);               // [32][33] overlay; col 32 = 1/sum
  unsigned short* pb = xs + 2112;                         // P bf16 [32][32] overlay (byte 4224)
  const int lane = tid & 63, wave = tid >> 6;
  const int l15 = lane & 15, quad = lane >> 4;

  for (int i = tid; i < 4096; i += 256) {                 // vectorized x load
    int t = i >> 7, c = (i & 127) << 2;
    float4 e4 = *reinterpret_cast<const float4*>(g + (size_t)b * 16384 + ((size_t)i << 2));
    short4v s; s[0] = f2us(e4.x); s[1] = f2us(e4.y); s[2] = f2us(e4.z); s[3] = f2us(e4.w);
    *reinterpret_cast<short4v*>(xs + t * XS_STR + c) = s;
  }
  __syncthreads();
  // ---- QKV MFMA ----
  {
    int wrowi[6];
#pragma unroll
    for (int ni = 0; ni < 6; ++ni) {
      int idx = (wave + ni * 4) * 16 + l15;
      int m = idx >> 7, dd = idx & 127;
      wrowi[ni] = m * 512 + h * 128 + dd;
    }
    float4v acc[6][2];
#pragma unroll
    for (int ni = 0; ni < 6; ++ni)
#pragma unroll
      for (int mt = 0; mt < 2; ++mt) acc[ni][mt] = (float4v){0.f, 0.f, 0.f, 0.f};
    for (int kc4 = 0; kc4 < 4; ++kc4) {
      short8v af[2][4];
#pragma unroll
      for (int mt = 0; mt < 2; ++mt)
#pragma unroll
        for (int u = 0; u < 4; ++u)
          af[mt][u] = *reinterpret_cast<const short8v*>(
              xs + (mt * 16 + l15) * XS_STR + kc4 * 128 + u * 32 + quad * 8);
#pragma unroll
      for (int ni = 0; ni < 6; ++ni) {
        const unsigned short* wrow = twb + (size_t)wrowi[ni] * 512 + kc4 * 128;
#pragma unroll
        for (int u = 0; u < 4; ++u) {
          short8v bfr = *reinterpret_cast<const short8v*>(wrow + u * 32 + quad * 8);
          acc[ni][0] = MFMA16(af[0][u], bfr, acc[ni][0], 0, 0, 0);
          acc[ni][1] = MFMA16(af[1][u], bfr, acc[ni][1], 0, 0, 0);
        }
      }
    }
#pragma unroll
    for (int ni = 0; ni < 6; ++ni) {
      int idx = (wave + ni * 4) * 16 + l15;
      int m = idx >> 7, dd = idx & 127;
      float bj = Bv[wrowi[ni]];
      if (m < 2) {
        unsigned short* dst = (m == 0) ? qs : ks;
#pragma unroll
        for (int r = 0; r < 4; ++r) {
          int t0 = quad * 4 + r;
          dst[t0 * 136 + dd] = f2us(acc[ni][0][r] + bj);
          dst[(t0 + 16) * 136 + dd] = f2us(acc[ni][1][r] + bj);
        }
      } else {                                            // V transposed: vT[d][k]
        short4v s0, s1;
#pragma unroll
        for (int r = 0; r < 4; ++r) { s0[r] = f2us(acc[ni][0][r] + bj); s1[r] = f2us(acc[ni][1][r] + bj); }
        *reinterpret_cast<short4v*>(vT + dd * 40 + quad * 4) = s0;
        *reinterpret_cast<short4v*>(vT + dd * 40 + 16 + quad * 4) = s1;
      }
    }
  }
  __syncthreads();
  // ---- scores MFMA: wave -> tile (mt,nt); S = Q.K^T (M=32,N=32,K=128) ----
  {
    const float scale2 = 0.08838834764831845f;            // 1/sqrt(128)
    const int mt = wave >> 1, nt = wave & 1;
    float4v acc = {0.f, 0.f, 0.f, 0.f};
#pragma unroll
    for (int kc = 0; kc < 4; ++kc) {
      short8v qf = *reinterpret_cast<const short8v*>(qs + (mt * 16 + l15) * 136 + kc * 32 + quad * 8);
      short8v kf = *reinterpret_cast<const short8v*>(ks + (nt * 16 + l15) * 136 + kc * 32 + quad * 8);
      acc = MFMA16(qf, kf, acc, 0, 0, 0);
    }
#pragma unroll
    for (int r = 0; r < 4; ++r)
      sc[(mt * 16 + quad * 4 + r) * 33 + nt * 16 + l15] = acc[r] * scale2;
  }
  __syncthreads();
  // ---- softmax rows: 4 lanes/row, shfl-reduce; bf16 unnormalized P ----
  if (tid < 128) {
    int row = tid >> 2, seg = tid & 3;
    float* srow = sc + row * 33;
    float mx = srow[seg * 8];
#pragma unroll
    for (int c = 1; c < 8; ++c) mx = fmaxf(mx, srow[seg * 8 + c]);
    mx = fmaxf(mx, __shfl_xor(mx, 1));
    mx = fmaxf(mx, __shfl_xor(mx, 2));
    float s = 0.f;
    short8v pv;
#pragma unroll
    for (int c = 0; c < 8; ++c) {
      float e = expf(srow[seg * 8 + c] - mx);
      s += e; pv[c] = f2us(e);
    }
    *reinterpret_cast<short8v*>(pb + row * 32 + seg * 8) = pv;
    s += __shfl_xor(s, 1);
    s += __shfl_xor(s, 2);
    if (seg == 0) srow[32] = 1.f / s;
  }
  __syncthreads();
  // ---- PV MFMA: O = P.V (M=32,N=128,K=32); wave handles n-tiles 2w,2w+1 ----
  {
    short8v pf[2], vf[2];
#pragma unroll
    for (int mt = 0; mt < 2; ++mt)
      pf[mt] = *reinterpret_cast<const short8v*>(pb + (mt * 16 + l15) * 32 + quad * 8);
#pragma unroll
    for (int ntl = 0; ntl < 2; ++ntl)
      vf[ntl] = *reinterpret_cast<const short8v*>(vT + ((2 * wave + ntl) * 16 + l15) * 40 + quad * 8);
    float4v acc[2][2];
#pragma unroll
    for (int mt = 0; mt < 2; ++mt)
#pragma unroll
      for (int ntl = 0; ntl < 2; ++ntl) {
        acc[mt][ntl] = (float4v){0.f, 0.f, 0.f, 0.f};
        acc[mt][ntl] = MFMA16(pf[mt], vf[ntl], acc[mt][ntl], 0, 0, 0);
      }
#pragma unroll
    for (int mt = 0; mt < 2; ++mt)
#pragma unroll
      for (int r = 0; r < 4; ++r) {
        int q = mt * 16 + quad * 4 + r;
        float inv = sc[q * 33 + 32];
#pragma unroll
        for (int ntl = 0; ntl < 2; ++ntl)
          attn[((size_t)b * 32 + q) * 512 + h * 128 + (2 * wave + ntl) * 16 + l15] =
              acc[mt][ntl][r] * inv;
      }
  }
}

// ---------------------------------------------------------------------------
// proj GEMM via MFMA (M=16/block, N=512, K=512) + bias + residual + LN.
// ---------------------------------------------------------------------------
__global__ __launch_bounds__(256, 2) void k_projln_mfma(
    const float* __restrict__ X, const unsigned short* __restrict__ Wb,
    const float* __restrict__ bias, const float* __restrict__ res,
    const float* __restrict__ gam, const float* __restrict__ bet,
    float* __restrict__ Y)
{
  const int row0 = blockIdx.x * 16, tid = threadIdx.x;
  __shared__ alignas(16) unsigned short xs[16 * 520];
  __shared__ float ys[16 * 516];
  for (int i = tid; i < 16 * 512; i += 256) {
    int t = i >> 9, c = i & 511;
    xs[t * 520 + c] = f2us(X[(size_t)(row0 + t) * 512 + c]);
  }
  __syncthreads();
  {
    const int lane = tid & 63, wave = tid >> 6;
    const int l15 = lane & 15, quad = lane >> 4;
    short8v af[16];
#pragma unroll
    for (int kc = 0; kc < 16; ++kc)
      af[kc] = *reinterpret_cast<const short8v*>(xs + l15 * 520 + kc * 32 + quad * 8);
    for (int ni = 0; ni < 8; ++ni) {
      int col = (wave + ni * 4) * 16 + l15;
      const unsigned short* wrow = Wb + (size_t)col * 512;
      float4v acc = {0.f,0.f,0.f,0.f};
#pragma unroll
      for (int kc = 0; kc < 16; ++kc) {
        short8v bfr = *reinterpret_cast<const short8v*>(wrow + kc * 32 + quad * 8);
        acc = MFMA16(af[kc], bfr, acc, 0, 0, 0);
      }
      float bj = bias[col];
#pragma unroll
      for (int r = 0; r < 4; ++r)
        ys[(quad * 4 + r) * 516 + col] = acc[r] + bj;
    }
  }
  __syncthreads();
  for (int i = tid; i < 16 * 512; i += 256) {
    int t = i >> 9, c = i & 511;
    ys[t * 516 + c] += res[(size_t)(row0 + t) * 512 + c];
  }
  __syncthreads();
  {
    int row = tid >> 4, l16 = tid & 15;
    const float* yr = ys + row * 516;
    float part = 0.f;
#pragma unroll
    for (int k = 0; k < 32; ++k) part += yr[l16 + 16 * k];
#pragma unroll
    for (int off = 8; off; off >>= 1) part += __shfl_xor(part, off, 16);
    float mean = part * (1.f / 512.f);
    float var = 0.f;
#pragma unroll
    for (int k = 0; k < 32; ++k) { float d = yr[l16 + 16 * k] - mean; var += d * d; }
#pragma unroll
    for (int off = 8; off; off >>= 1) var += __shfl_xor(var, off, 16);
    float rs = rsqrtf(var * (1.f / 512.f) + 1e-5f);
    for (int k = 0; k < 32; ++k) {
      int c = l16 + 16 * k;
      Y[(size_t)(row0 + row) * 512 + c] = (yr[c] - mean) * rs * gam[c] + bet[c];
    }
  }
}

// ---------------------------------------------------------------------------
// ff1 GEMM via MFMA (M=16/block, N=1024, K=512) + bias + relu -> bf16.
// ---------------------------------------------------------------------------
__global__ __launch_bounds__(256, 2) void k_ff1_mfma(
    const float* __restrict__ X, const unsigned short* __restrict__ Wb,
    const float* __restrict__ bias, unsigned short* __restrict__ Y)
{
  const int row0 = blockIdx.x * 16, tid = threadIdx.x;
  __shared__ alignas(16) unsigned short xs[16 * 520];
  for (int i = tid; i < 16 * 512; i += 256) {
    int t = i >> 9, c = i & 511;
    xs[t * 520 + c] = f2us(X[(size_t)(row0 + t) * 512 + c]);
  }
  __syncthreads();
  const int lane = tid & 63, wave = tid >> 6;
  const int l15 = lane & 15, quad = lane >> 4;
  short8v af[16];
#pragma unroll
  for (int kc = 0; kc < 16; ++kc)
    af[kc] = *reinterpret_cast<const short8v*>(xs + l15 * 520 + kc * 32 + quad * 8);
  for (int ni = 0; ni < 16; ++ni) {
    int col = (wave + ni * 4) * 16 + l15;
    const unsigned short* wrow = Wb + (size_t)col * 512;
    float4v acc = {0.f,0.f,0.f,0.f};
#pragma unroll
    for (int kc = 0; kc < 16; ++kc) {
      short8v bfr = *reinterpret_cast<const short8v*>(wrow + kc * 32 + quad * 8);
      acc = MFMA16(af[kc], bfr, acc, 0, 0, 0);
    }
    float bj = bias[col];
#pragma unroll
    for (int r = 0; r < 4; ++r)
      Y[(size_t)(row0 + quad * 4 + r) * 1024 + col] = f2us(fmaxf(acc[r] + bj, 0.f));
  }
}

// ---------------------------------------------------------------------------
// ff2 GEMM via MFMA (M=16/block, N=512, K=1024 in 2 chunks) + bias +
// residual + LN. Y fp32 overlays X bf16 in-place.
// ---------------------------------------------------------------------------
__global__ __launch_bounds__(256, 2) void k_ff2ln_mfma(
    const unsigned short* __restrict__ X, const unsigned short* __restrict__ Wb,
    const float* __restrict__ bias, const float* __restrict__ res,
    const float* __restrict__ gam, const float* __restrict__ bet,
    float* __restrict__ Y)
{
  const int row0 = blockIdx.x * 16, tid = threadIdx.x;
  __shared__ alignas(16) unsigned short xs[16 * 520];
  __shared__ float ys[16 * 516];
  const int lane = tid & 63, wave = tid >> 6;
  const int l15 = lane & 15, quad = lane >> 4;
  float4v acc[8];
#pragma unroll
  for (int ni = 0; ni < 8; ++ni) acc[ni] = (float4v){0.f,0.f,0.f,0.f};
  for (int half = 0; half < 2; ++half) {
    __syncthreads();
    for (int i = tid; i < 16 * 512; i += 256) {
      int t = i >> 9, c = i & 511;
      xs[t * 520 + c] = X[(size_t)(row0 + t) * 1024 + half * 512 + c];
    }
    __syncthreads();
    short8v af[16];
#pragma unroll
    for (int kc = 0; kc < 16; ++kc)
      af[kc] = *reinterpret_cast<const short8v*>(xs + l15 * 520 + kc * 32 + quad * 8);
#pragma unroll
    for (int ni = 0; ni < 8; ++ni) {
      int col = (wave + ni * 4) * 16 + l15;
      const unsigned short* wrow = Wb + (size_t)col * 1024 + half * 512;
#pragma unroll
      for (int kc = 0; kc < 16; ++kc) {
        short8v bfr = *reinterpret_cast<const short8v*>(wrow + kc * 32 + quad * 8);
        acc[ni] = MFMA16(af[kc], bfr, acc[ni], 0, 0, 0);
      }
    }
  }
  __syncthreads();
  for (int ni = 0; ni < 8; ++ni) {
    int col = (wave + ni * 4) * 16 + l15;
    float bj = bias[col];
#pragma unroll
    for (int r = 0; r < 4; ++r)
      ys[(quad * 4 + r) * 516 + col] = acc[ni][r] + bj;
  }
  __syncthreads();
  for (int i = tid; i < 16 * 512; i += 256) {
    int t = i >> 9, c = i & 511;
    ys[t * 516 + c] += res[(size_t)(row0 + t) * 512 + c];
  }
  __syncthreads();
  {
    int row = tid >> 4, l16 = tid & 15;
    const float* yr = ys + row * 516;
    float part = 0.f;
#pragma unroll
    for (int k = 0; k < 32; ++k) part += yr[l16 + 16 * k];
#pragma unroll
    for (int off = 8; off; off >>= 1) part += __shfl_xor(part, off, 16);
    float mean = part * (1.f / 512.f);
    float var = 0.f;
#pragma unroll
    for (int k = 0; k < 32; ++k) { float d = yr[l16 + 16 * k] - mean; var += d * d; }
#pragma unroll
    for (int off = 8; off; off >>= 1) var += __shfl_xor(var, off, 16);
    float rs = rsqrtf(var * (1.f / 512.f) + 1e-5f);
    for (int k = 0; k < 32; ++k) {
      int c = l16 + 16 * k;
      Y[(size_t)(row0 + row) * 512 + c] = (yr[c] - mean) * rs * gam[c] + bet[c];
    }
  }
}

// ---------------------------------------------------------------------------
// Final: mean-pool, temporal MLP, concat, classifier, LN, relu -> fp32
// ---------------------------------------------------------------------------
__global__ __launch_bounds__(256) void k_final(
    const float* __restrict__ g2,
    const float* __restrict__ db, const float* __restrict__ dsl,
    const float* __restrict__ te1_w, const float* __restrict__ te1_b,
    const float* __restrict__ l1g, const float* __restrict__ l1b,
    const float* __restrict__ te2_w, const float* __restrict__ te2_b,
    const float* __restrict__ l2g, const float* __restrict__ l2b,
    const float* __restrict__ c_w, const float* __restrict__ c_b,
    const float* __restrict__ clg, const float* __restrict__ clb,
    float* __restrict__ out)
{
  const int b = blockIdx.x, tid = threadIdx.x;
  __shared__ float cat[640];
  __shared__ float t1[64];
  __shared__ float t2[128];
  __shared__ float pre[256];
  __shared__ float red[256];
  __shared__ float st[2];
  for (int i = tid; i < 512; i += 256) {
    float acc = 0.f;
#pragma unroll
    for (int t = 0; t < 32; ++t) acc += g2[((size_t)b * 32 + t) * 512 + i];
    cat[i] = acc * (1.f / 32.f);
  }
  if (tid == 0) {
    float s = 0.f;
    for (int i = 0; i < 31; ++i) s += db[b * 31 + i];
    st[0] = s / 31.f;
    st[1] = dsl[b];
  }
  __syncthreads();
  const float f0 = st[0], f1v = st[1];
  if (tid < 64)
    t1[tid] = f0 * te1_w[tid * 2] + f1v * te1_w[tid * 2 + 1] + te1_b[tid];
  __syncthreads();
  if (tid == 0) {
    float m = 0.f; for (int i = 0; i < 64; ++i) m += t1[i]; m *= (1.f / 64.f);
    float v = 0.f; for (int i = 0; i < 64; ++i) { float d = t1[i] - m; v += d * d; }
    st[0] = m; st[1] = rsqrtf(v * (1.f / 64.f) + 1e-5f);
  }
  __syncthreads();
  if (tid < 64) {
    float v = (t1[tid] - st[0]) * st[1] * l1g[tid] + l1b[tid];
    t1[tid] = fmaxf(v, 0.f);
  }
  __syncthreads();
  if (tid < 128)
    t2[tid] = dot_ff(t1, te2_w + (size_t)tid * 64, 64) + te2_b[tid];
  __syncthreads();
  if (tid == 0) {
    float m = 0.f; for (int i = 0; i < 128; ++i) m += t2[i]; m *= (1.f / 128.f);
    float v = 0.f; for (int i = 0; i < 128; ++i) { float d = t2[i] - m; v += d * d; }
    st[0] = m; st[1] = rsqrtf(v * (1.f / 128.f) + 1e-5f);
  }
  __syncthreads();
  if (tid < 128) {
    float v = (t2[tid] - st[0]) * st[1] * l2g[tid] + l2b[tid];
    cat[512 + tid] = fmaxf(v, 0.f);
  }
  __syncthreads();
  pre[tid] = dot_ff(cat, c_w + (size_t)tid * 640, 640) + c_b[tid];
  red[tid] = pre[tid];
  __syncthreads();
  for (int s = 128; s > 0; s >>= 1) { if (tid < s) red[tid] += red[tid + s]; __syncthreads(); }
  const float m = red[0] * (1.f / 256.f);
  __syncthreads();
  const float d = pre[tid] - m;
  red[tid] = d * d;
  __syncthreads();
  for (int s = 128; s > 0; s >>= 1) { if (tid < s) red[tid] += red[tid + s]; __syncthreads(); }
  const float rs = rsqrtf(red[0] * (1.f / 256.f) + 1e-5f);
  float v = d * rs * clg[tid] + clb[tid];
  out[(size_t)b * 256 + tid] = fmaxf(v, 0.f);
}

// ---------------------------------------------------------------------------
extern "C" void kernel_launch(void* const* d_in, const int* in_sizes, int n_in,
                              void* d_out, int out_size, void* d_ws, size_t ws_size,
                              hipStream_t stream) {
  (void)in_sizes; (void)n_in; (void)out_size; (void)ws_size;
  const int*   oh     = (const int*)  d_in[0];
  const float* db     = (const float*)d_in[1];
  const float* dsl    = (const float*)d_in[2];
  const float* emb    = (const float*)d_in[3];
  const float* a_in_w = (const float*)d_in[4];
  const float* a_in_b = (const float*)d_in[5];
  const float* a_out_w= (const float*)d_in[6];
  const float* a_out_b= (const float*)d_in[7];
  const float* wih_f  = (const float*)d_in[8];
  const float* whh_f  = (const float*)d_in[9];
  const float* bih_f  = (const float*)d_in[10];
  const float* bhh_f  = (const float*)d_in[11];
  const float* wih_b  = (const float*)d_in[12];
  const float* whh_b  = (const float*)d_in[13];
  const float* bih_b  = (const float*)d_in[14];
  const float* bhh_b  = (const float*)d_in[15];
  const float* t_in_w = (const float*)d_in[16];
  const float* t_in_b = (const float*)d_in[17];
  const float* t_out_w= (const float*)d_in[18];
  const float* t_out_b= (const float*)d_in[19];
  const float* t_ln1g = (const float*)d_in[20];
  const float* t_ln1b = (const float*)d_in[21];
  const float* t_ff1w = (const float*)d_in[22];
  const float* t_ff1b = (const float*)d_in[23];
  const float* t_ff2w = (const float*)d_in[24];
  const float* t_ff2b = (const float*)d_in[25];
  const float* t_ln2g = (const float*)d_in[26];
  const float* t_ln2b = (const float*)d_in[27];
  const float* te1_w  = (const float*)d_in[28];
  const float* te1_b  = (const float*)d_in[29];
  const float* tl1g   = (const float*)d_in[30];
  const float* tl1b   = (const float*)d_in[31];
  const float* te2_w  = (const float*)d_in[32];
  const float* te2_b  = (const float*)d_in[33];
  const float* tl2g   = (const float*)d_in[34];
  const float* tl2b   = (const float*)d_in[35];
  const float* c_w    = (const float*)d_in[36];
  const float* c_b    = (const float*)d_in[37];
  const float* clng   = (const float*)d_in[38];
  const float* clnb   = (const float*)d_in[39];

  float* ws = (float*)d_ws;
  // Workspace (float slots), max index 17,391,616 (~69.6 MB):
  //   A [0,        1048576): oe [8192,128] fp32
  //   B [1048576,  5242880): g fp32 -> f1 bf16 (over dead g) -> g2 fp32
  //   C [5242880,  9437184): attn fp32; g1 = LN out in-place
  //   D [9437184,  9633792): whhb bf16 [2][768][256]
  //   D2[9633792,  9732096): wihb bf16 [2][768][128]
  //   E [10027008,10051584): awb bf16 [384*128]
  //   F [10051584,10444800): twb bf16 [1536*512]
  //   G [10444800,10575872): pwb bf16 [512*512]
  //   G2[10575872,10838016): f1wb bf16 [1024*512]
  //   G3[10838016,11100160): f2wb bf16 [512*1024]
  //   H [11100160,17391616): gi bf16 [8192*1536]
  float* oe   = ws;
  float* g    = ws + 1048576;
  float* attn = ws + 5242880;
  float* g1   = attn;                                   // in-place
  unsigned short* f1 = (unsigned short*)(ws + 1048576); // over dead g
  float* g2   = ws + 1048576;                           // in-place over f1
  unsigned short* whhb = (unsigned short*)(ws + 9437184);
  unsigned short* wihb = (unsigned short*)(ws + 9633792);
  unsigned short* awb  = (unsigned short*)(ws + 10027008);
  unsigned short* twb  = (unsigned short*)(ws + 10051584);
  unsigned short* pwb  = (unsigned short*)(ws + 10444800);
  unsigned short* f1wb = (unsigned short*)(ws + 10575872);
  unsigned short* f2wb = (unsigned short*)(ws + 10838016);
  unsigned short* gi   = (unsigned short*)(ws + 11100160);

  k_canary<<<256, 256, 0, stream>>>((float*)d_out);
  k_cvt<<<3072, 256, 0, stream>>>(a_in_w, t_in_w, t_out_w, t_ff1w, t_ff2w,
                                  awb, twb, pwb, f1wb, f2wb);
  k_gru_wb<<<1536, 256, 0, stream>>>(wih_f, whh_f, wih_b, whh_b, whhb, wihb);
  k_order_attn<<<8192, 256, 0, stream>>>(oh, emb, awb, a_in_b, a_out_w, a_out_b, oe);
  k_gru_gi<<<256, 256, 0, stream>>>(oe, wihb, gi);
  k_gru_rec<<<dim3(32, 2), 512, 0, stream>>>(gi, whhb, bih_f, bhh_f, bih_b, bhh_b, g);
  k_mha2f<<<dim3(256, 4), 256, 0, stream>>>(g, twb, t_in_b, attn);
  k_projln_mfma<<<512, 256, 0, stream>>>(attn, pwb, t_out_b, g, t_ln1g, t_ln1b, g1);
  k_ff1_mfma<<<512, 256, 0, stream>>>(g1, f1wb, t_ff1b, f1);
  k_ff2ln_mfma<<<512, 256, 0, stream>>>(f1, f2wb, t_ff2b, g1, t_ln2g, t_ln2b, g2);
  k_final<<<256, 256, 0, stream>>>(g2, db, dsl, te1_w, te1_b, tl1g, tl1b,
                                   te2_w, te2_b, tl2g, tl2b, c_w, c_b, clng, clnb,
                                   (float*)d_out);
}

// Round 3
// 635.458 us; speedup vs baseline: 1.2996x; 1.1277x over previous
//
#include <hip/hip_runtime.h>
#include <hip/hip_bf16.h>
#include <math.h>

typedef __hip_bfloat16 bf16;
typedef __attribute__((ext_vector_type(8))) short short8v;   // 8 bf16 (4 VGPRs)
typedef __attribute__((ext_vector_type(4))) short short4v;   // 4 bf16 (2 VGPRs)
typedef __attribute__((ext_vector_type(4))) float float4v;   // 4 fp32 acc
#define MFMA16 __builtin_amdgcn_mfma_f32_16x16x32_bf16

__device__ __forceinline__ float us2f(unsigned short u) {
  union { unsigned u; float f; } c; c.u = ((unsigned)u) << 16; return c.f;
}
__device__ __forceinline__ unsigned short f2us(float f) {
  return __bfloat16_as_ushort(__float2bfloat16(f));
}

// fp32 x . fp32 w, K % 8 == 0, 16B-aligned
__device__ __forceinline__ float dot_ff(const float* __restrict__ x,
                                        const float* __restrict__ w, int K) {
  const float4* xp = reinterpret_cast<const float4*>(x);
  const float4* wp = reinterpret_cast<const float4*>(w);
  float acc = 0.f;
  const int n = K >> 2;
  for (int i = 0; i < n; ++i) {
    float4 a = xp[i], b = wp[i];
    acc += a.x*b.x + a.y*b.y + a.z*b.z + a.w*b.w;
  }
  return acc;
}

__device__ __forceinline__ float sigm(float x) { return 1.f / (1.f + expf(-x)); }

// ---------------------------------------------------------------------------
__global__ void k_canary(float* __restrict__ out) {
  out[blockIdx.x * 256 + threadIdx.x] = 100.0f;
}

// ---------------------------------------------------------------------------
// One-shot: convert MFMA-consumed weights to bf16 in ws.
// ---------------------------------------------------------------------------
__global__ __launch_bounds__(256) void k_cvt(
    const float* __restrict__ a_in_w, const float* __restrict__ t_in_w,
    const float* __restrict__ t_out_w, const float* __restrict__ t_ff1w,
    const float* __restrict__ t_ff2w, const float* __restrict__ a_out_w,
    unsigned short* __restrict__ awb, unsigned short* __restrict__ twb,
    unsigned short* __restrict__ pwb, unsigned short* __restrict__ f1wb,
    unsigned short* __restrict__ f2wb, unsigned short* __restrict__ awb2)
{
  int i = blockIdx.x * 256 + threadIdx.x;
  if (i < 49152)  awb[i] = f2us(a_in_w[i]);
  if (i < 786432) twb[i] = f2us(t_in_w[i]);
  if (i < 262144) pwb[i] = f2us(t_out_w[i]);
  if (i < 524288) f1wb[i] = f2us(t_ff1w[i]);
  if (i < 524288) f2wb[i] = f2us(t_ff2w[i]);
  if (i < 16384)  awb2[i] = f2us(a_out_w[i]);
}

// ---------------------------------------------------------------------------
// GRU weight prep: row-major bf16 copies. whhb [dir][768][256],
// wihb [dir][768][128] (for gi GEMM).
// ---------------------------------------------------------------------------
__global__ __launch_bounds__(256) void k_gru_wb(
    const float* __restrict__ wih_f, const float* __restrict__ whh_f,
    const float* __restrict__ wih_b, const float* __restrict__ whh_b,
    unsigned short* __restrict__ whhb, unsigned short* __restrict__ wihb)
{
  int i = blockIdx.x * 256 + threadIdx.x;   // < 393216
  if (i >= 393216) return;
  int dir = i / 196608, r = i % 196608;
  whhb[i] = f2us((dir ? whh_b : whh_f)[r]);
  if (r < 98304) wihb[dir * 98304 + r] = f2us((dir ? wih_b : wih_f)[r]);
}

// ---------------------------------------------------------------------------
// Stage 1: embed + per-order MHA + proj-then-mean (mean(O)W^T == mean(OW^T)).
// QKV MFMA -> fused scores/softmax/PV (wave = head, barrier-free: each wave
// touches only its own head's column stripe of qb for the O overlay) ->
// out-proj MFMA + shfl mean. 4 barriers total.
// LDS: ids 128 + xs 8704 (P overlay) + qb 8704 (O overlay) + kb 8704
//      + vT 10240 = 36,480 B -> 4 blocks/CU.
// ---------------------------------------------------------------------------
__global__ __launch_bounds__(256, 4) void k_order_attn(
    const int* __restrict__ oh, const float* __restrict__ emb,
    const unsigned short* __restrict__ awb, const float* __restrict__ in_b,
    const unsigned short* __restrict__ awb2, const float* __restrict__ out_b,
    float* __restrict__ order_emb)
{
  const int bo = blockIdx.x;            // 0..8191
  const int tid = threadIdx.x;
  __shared__ int ids[32];
  __shared__ alignas(16) unsigned short xs[32 * 136];     // x bf16; P [128][32] overlays
  __shared__ alignas(16) unsigned short qb[32 * 136];     // q bf16; O bf16 [32][136] overlays
  __shared__ alignas(16) unsigned short kb[32 * 136];
  __shared__ alignas(16) unsigned short vT[128 * 40];     // V^T bf16: vT[d][k]
  unsigned short* pb = xs;                                // P overlay (8192 <= 8704)
  unsigned short* ob = qb;                                // O overlay

  const int lane = tid & 63, wave = tid >> 6;
  const int l15 = lane & 15, quad = lane >> 4;

  if (tid < 32) ids[tid] = oh[bo * 32 + tid];
  __syncthreads();
  for (int i = tid; i < 1024; i += 256) {                 // vectorized gather
    int t = i >> 5, d4 = (i & 31) << 2;
    float4 e4 = *reinterpret_cast<const float4*>(emb + (size_t)ids[t] * 128 + d4);
    short4v s; s[0] = f2us(e4.x); s[1] = f2us(e4.y); s[2] = f2us(e4.z); s[3] = f2us(e4.w);
    *reinterpret_cast<short4v*>(xs + t * 136 + d4) = s;
  }
  __syncthreads();
  // ---- QKV MFMA: qkv[t][j] = x[t][.] . w[j][.] ----
  {
    short8v af[2][4];
#pragma unroll
    for (int mt = 0; mt < 2; ++mt)
#pragma unroll
      for (int kc = 0; kc < 4; ++kc)
        af[mt][kc] = *reinterpret_cast<const short8v*>(
            xs + (mt * 16 + l15) * 136 + kc * 32 + quad * 8);
    for (int ni = 0; ni < 6; ++ni) {
      const int j = (wave + ni * 4) * 16 + l15;
      const unsigned short* wrow = awb + (size_t)j * 128;
      float4v acc0 = {0.f, 0.f, 0.f, 0.f}, acc1 = {0.f, 0.f, 0.f, 0.f};
#pragma unroll
      for (int kc = 0; kc < 4; ++kc) {
        short8v bfr = *reinterpret_cast<const short8v*>(wrow + kc * 32 + quad * 8);
        acc0 = MFMA16(af[0][kc], bfr, acc0, 0, 0, 0);
        acc1 = MFMA16(af[1][kc], bfr, acc1, 0, 0, 0);
      }
      const float bj = in_b[j];
      const int jj = j & 127;
      if (j < 256) {
        unsigned short* dst = (j < 128) ? qb : kb;
#pragma unroll
        for (int r = 0; r < 4; ++r) {
          int t0 = quad * 4 + r;
          dst[t0 * 136 + jj] = f2us(acc0[r] + bj);
          dst[(t0 + 16) * 136 + jj] = f2us(acc1[r] + bj);
        }
      } else {                                            // V transposed: vT[d][k]
        short4v s0, s1;
#pragma unroll
        for (int r = 0; r < 4; ++r) { s0[r] = f2us(acc0[r] + bj); s1[r] = f2us(acc1[r] + bj); }
        *reinterpret_cast<short4v*>(vT + jj * 40 + quad * 4) = s0;
        *reinterpret_cast<short4v*>(vT + jj * 40 + 16 + quad * 4) = s1;
      }
    }
  }
  __syncthreads();
  // ---- FUSED: scores + softmax + PV + O write (wave = head h) ----
  {
    const int h = wave;
    const float scale1 = 0.17677669529663687f;            // 1/sqrt(32)
    short8v qf[2], kf[2];
#pragma unroll
    for (int mt = 0; mt < 2; ++mt)
      qf[mt] = *reinterpret_cast<const short8v*>(qb + (mt * 16 + l15) * 136 + h * 32 + quad * 8);
#pragma unroll
    for (int nt = 0; nt < 2; ++nt)
      kf[nt] = *reinterpret_cast<const short8v*>(kb + (nt * 16 + l15) * 136 + h * 32 + quad * 8);
    float4v sacc[2][2];
#pragma unroll
    for (int mt = 0; mt < 2; ++mt)
#pragma unroll
      for (int nt = 0; nt < 2; ++nt) {
        sacc[mt][nt] = (float4v){0.f, 0.f, 0.f, 0.f};
        sacc[mt][nt] = MFMA16(qf[mt], kf[nt], sacc[mt][nt], 0, 0, 0);
      }
    // softmax per row (row elements across the 16 lanes of one quad, x2 nt)
    float inv_reg[2][4];
#pragma unroll
    for (int mt = 0; mt < 2; ++mt)
#pragma unroll
      for (int r = 0; r < 4; ++r) {
        float s0 = sacc[mt][0][r] * scale1;
        float s1 = sacc[mt][1][r] * scale1;
        float mx = fmaxf(s0, s1);
        mx = fmaxf(mx, __shfl_xor(mx, 1));
        mx = fmaxf(mx, __shfl_xor(mx, 2));
        mx = fmaxf(mx, __shfl_xor(mx, 4));
        mx = fmaxf(mx, __shfl_xor(mx, 8));
        float e0 = expf(s0 - mx), e1 = expf(s1 - mx);
        float sm = e0 + e1;
        sm += __shfl_xor(sm, 1);
        sm += __shfl_xor(sm, 2);
        sm += __shfl_xor(sm, 4);
        sm += __shfl_xor(sm, 8);
        inv_reg[mt][r] = 1.f / sm;
        int row = h * 32 + mt * 16 + quad * 4 + r;
        pb[row * 32 + l15] = f2us(e0);
        pb[row * 32 + 16 + l15] = f2us(e1);
      }
    // PV (reads only this wave's P rows / vT stripe -> no barrier needed)
    short8v pf[2], vf[2];
#pragma unroll
    for (int mt = 0; mt < 2; ++mt)
      pf[mt] = *reinterpret_cast<const short8v*>(pb + (h * 32 + mt * 16 + l15) * 32 + quad * 8);
#pragma unroll
    for (int nt = 0; nt < 2; ++nt)
      vf[nt] = *reinterpret_cast<const short8v*>(vT + (h * 32 + nt * 16 + l15) * 40 + quad * 8);
    float4v oacc[2][2];
#pragma unroll
    for (int mt = 0; mt < 2; ++mt)
#pragma unroll
      for (int nt = 0; nt < 2; ++nt) {
        oacc[mt][nt] = (float4v){0.f, 0.f, 0.f, 0.f};
        oacc[mt][nt] = MFMA16(pf[mt], vf[nt], oacc[mt][nt], 0, 0, 0);
      }
    // write O bf16 into ob (qb overlay): only this wave's head-col stripe,
    // which is exactly the stripe this wave read its q-frags from.
#pragma unroll
    for (int mt = 0; mt < 2; ++mt)
#pragma unroll
      for (int r = 0; r < 4; ++r) {
        int t = mt * 16 + quad * 4 + r;
        float inv = inv_reg[mt][r];
#pragma unroll
        for (int nt = 0; nt < 2; ++nt)
          ob[t * 136 + h * 32 + nt * 16 + l15] = f2us(oacc[mt][nt][r] * inv);
      }
  }
  __syncthreads();
  // ---- out-proj MFMA: proj[t][j] = O[t][.] . W[j][.]; then mean over t ----
  {
    float4v acc[2][2];
#pragma unroll
    for (int mt = 0; mt < 2; ++mt)
#pragma unroll
      for (int nt = 0; nt < 2; ++nt) acc[mt][nt] = (float4v){0.f, 0.f, 0.f, 0.f};
#pragma unroll
    for (int kc = 0; kc < 4; ++kc) {
      short8v af0 = *reinterpret_cast<const short8v*>(ob + l15 * 136 + kc * 32 + quad * 8);
      short8v af1 = *reinterpret_cast<const short8v*>(ob + (16 + l15) * 136 + kc * 32 + quad * 8);
#pragma unroll
      for (int nt = 0; nt < 2; ++nt) {
        int j = (wave * 2 + nt) * 16 + l15;
        short8v bfr = *reinterpret_cast<const short8v*>(awb2 + (size_t)j * 128 + kc * 32 + quad * 8);
        acc[0][nt] = MFMA16(af0, bfr, acc[0][nt], 0, 0, 0);
        acc[1][nt] = MFMA16(af1, bfr, acc[1][nt], 0, 0, 0);
      }
    }
#pragma unroll
    for (int nt = 0; nt < 2; ++nt) {
      float part = 0.f;
#pragma unroll
      for (int mt = 0; mt < 2; ++mt)
#pragma unroll
        for (int r = 0; r < 4; ++r) part += acc[mt][nt][r];
      part += __shfl_xor(part, 16);
      part += __shfl_xor(part, 32);
      if (quad == 0) {
        int j = (wave * 2 + nt) * 16 + l15;
        order_emb[(size_t)bo * 128 + j] = part * (1.f / 32.f) + out_b[j];
      }
    }
  }
}

// ---------------------------------------------------------------------------
// gi GEMM (MFMA): gi[8192][1536] bf16 = oe @ wih^T (both dirs).
// ---------------------------------------------------------------------------
__global__ __launch_bounds__(256, 2) void k_gru_gi(
    const float* __restrict__ oe, const unsigned short* __restrict__ wihb,
    unsigned short* __restrict__ gi)
{
  const int row0 = blockIdx.x * 32, tid = threadIdx.x;
  __shared__ alignas(16) unsigned short xs[32 * 136];
  for (int i = tid; i < 32 * 128; i += 256) {
    int t = i >> 7, d = i & 127;
    xs[t * 136 + d] = f2us(oe[(size_t)(row0 + t) * 128 + d]);
  }
  __syncthreads();
  const int lane = tid & 63, wave = tid >> 6;
  const int l15 = lane & 15, quad = lane >> 4;
  short8v af[2][4];
#pragma unroll
  for (int mt = 0; mt < 2; ++mt)
#pragma unroll
    for (int kc = 0; kc < 4; ++kc)
      af[mt][kc] = *reinterpret_cast<const short8v*>(
          xs + (mt * 16 + l15) * 136 + kc * 32 + quad * 8);
  for (int ni = 0; ni < 24; ++ni) {
    int col = (wave + ni * 4) * 16 + l15;
    const unsigned short* wrow = wihb + (size_t)col * 128;
    float4v a0 = {0.f,0.f,0.f,0.f}, a1 = {0.f,0.f,0.f,0.f};
#pragma unroll
    for (int kc = 0; kc < 4; ++kc) {
      short8v bfr = *reinterpret_cast<const short8v*>(wrow + kc * 32 + quad * 8);
      a0 = MFMA16(af[0][kc], bfr, a0, 0, 0, 0);
      a1 = MFMA16(af[1][kc], bfr, a1, 0, 0, 0);
    }
#pragma unroll
    for (int r = 0; r < 4; ++r) {
      gi[(size_t)(row0 + quad * 4 + r) * 1536 + col] = f2us(a0[r]);
      gi[(size_t)(row0 + quad * 4 + r + 16) * 1536 + col] = f2us(a1[r]);
    }
  }
}

// ---------------------------------------------------------------------------
// GRU recurrence via MFMA. 2 batches/block, grid (128,2) = 256 blocks (all
// CUs), 512 threads (8 waves). MFMA M=16 rows; rows 2-15 stay zero. whh
// register-resident (192 VGPR of B-frags, loaded once). gi for step s+1
// prefetched into registers before the barrier -> global latency off the
// critical path. LDS: hb 8448 + pg 6176 = 14,624 B.
// ---------------------------------------------------------------------------
__global__ __launch_bounds__(512, 2) void k_gru_rec(
    const unsigned short* __restrict__ gi, const unsigned short* __restrict__ whhb,
    const float* __restrict__ bih_f, const float* __restrict__ bhh_f,
    const float* __restrict__ bih_b, const float* __restrict__ bhh_b,
    float* __restrict__ g)
{
  const int b0 = blockIdx.x * 2, dir = blockIdx.y;
  const int tid = threadIdx.x;           // 0..511
  const unsigned short* wb = whhb + (size_t)dir * 196608;   // [768][256] bf16
  const float* bih = dir ? bih_b : bih_f;
  const float* bhh = dir ? bhh_b : bhh_f;
  __shared__ alignas(16) unsigned short hb[16 * 264];   // h bf16 (A operand)
  __shared__ float pg[2 * 772];                         // gh fp32 (rows 0-1)
  const int lane = tid & 63, wave = tid >> 6;
  const int l15 = lane & 15, quad = lane >> 4;
  const int j = tid & 255, mb = tid >> 8;               // pointwise: (m=mb, j)
  const float bir = bih[j], biz = bih[256 + j], bin_ = bih[512 + j];
  const float bhr = bhh[j], bhz = bhh[256 + j], bhn  = bhh[512 + j];
  // preload whh B-frags (once)
  short8v wf[6][8];
  int cols[6];
#pragma unroll
  for (int ni = 0; ni < 6; ++ni) {
    cols[ni] = (wave + ni * 8) * 16 + l15;
#pragma unroll
    for (int kc = 0; kc < 8; ++kc)
      wf[ni][kc] = *reinterpret_cast<const short8v*>(
          wb + (size_t)cols[ni] * 256 + kc * 32 + quad * 8);
  }
  for (int i = tid; i < 16 * 264; i += 512) hb[i] = 0;
  // prefetch gi for s=0
  {
    int t0 = dir ? 31 : 0;
    size_t gb0 = ((size_t)(b0 + mb) * 32 + t0) * 1536 + dir * 768;
    // loads issued here; barrier below gives them time
    (void)gb0;
  }
  int tcur = dir ? 31 : 0;
  size_t gbase = ((size_t)(b0 + mb) * 32 + tcur) * 1536 + dir * 768;
  float gr = us2f(gi[gbase + j]);
  float gz = us2f(gi[gbase + 256 + j]);
  float gn = us2f(gi[gbase + 512 + j]);
  __syncthreads();
  for (int s = 0; s < 32; ++s) {
    float4v acc[6];
#pragma unroll
    for (int ni = 0; ni < 6; ++ni) acc[ni] = (float4v){0.f, 0.f, 0.f, 0.f};
#pragma unroll
    for (int kc = 0; kc < 8; ++kc) {
      short8v af = *reinterpret_cast<const short8v*>(hb + l15 * 264 + kc * 32 + quad * 8);
#pragma unroll
      for (int ni = 0; ni < 6; ++ni)
        acc[ni] = MFMA16(af, wf[ni][kc], acc[ni], 0, 0, 0);
    }
    if (quad == 0) {
#pragma unroll
      for (int ni = 0; ni < 6; ++ni) {
        pg[cols[ni]] = acc[ni][0];
        pg[772 + cols[ni]] = acc[ni][1];
      }
    }
    // prefetch gi for s+1 (consumed after the NEXT barrier -> latency hidden)
    float gr2 = 0.f, gz2 = 0.f, gn2 = 0.f;
    if (s < 31) {
      int t2 = dir ? (30 - s) : (s + 1);
      size_t gb2 = ((size_t)(b0 + mb) * 32 + t2) * 1536 + dir * 768;
      gr2 = us2f(gi[gb2 + j]);
      gz2 = us2f(gi[gb2 + 256 + j]);
      gn2 = us2f(gi[gb2 + 512 + j]);
    }
    __syncthreads();
    {
      const int tt = dir ? (31 - s) : s;
      float hprev = us2f(hb[mb * 264 + j]);
      float r = sigm(gr + bir + pg[mb * 772 + j] + bhr);
      float z = sigm(gz + biz + pg[mb * 772 + 256 + j] + bhz);
      float n = tanhf(gn + bin_ + r * (pg[mb * 772 + 512 + j] + bhn));
      float nh = (1.f - z) * n + z * hprev;
      hb[mb * 264 + j] = f2us(nh);
      g[((size_t)(b0 + mb) * 32 + tt) * 512 + dir * 256 + j] = nh;
    }
    gr = gr2; gz = gz2; gn = gn2;
    __syncthreads();
  }
}

// ---------------------------------------------------------------------------
// Stage 3 fused attention, one block per (b, head). x staged in K=256
// halves (xs2 16.9 KB) -> LDS 44,544 B -> 3 blocks/CU. QKV/scores/PV on
// MFMA; softmax (128 thr, 4 lanes/row shfl) emits unnormalized bf16 P,
// 1/sum folded into PV epilogue which writes attn directly.
// ---------------------------------------------------------------------------
#define XS2_STR 264

__global__ __launch_bounds__(256, 3) void k_mha2f(
    const float* __restrict__ g, const unsigned short* __restrict__ twb,
    const float* __restrict__ Bv, float* __restrict__ attn)
{
  const int b = blockIdx.x, h = blockIdx.y, tid = threadIdx.x;
  __shared__ alignas(16) unsigned short xs2[32 * XS2_STR]; // x half; sc+pb overlay
  __shared__ alignas(16) unsigned short qk[2 * 32 * 136];
  __shared__ alignas(16) unsigned short vT[128 * 40];      // vT[d][k]
  unsigned short* qs = qk;
  unsigned short* ks = qk + 32 * 136;
  float* sc = reinterpret_cast<float*>(xs2);               // [32][33]; col 32 = 1/sum
  unsigned short* pb = xs2 + 2112;                         // P bf16 [32][32] (byte 4224)
  const int lane = tid & 63, wave = tid >> 6;
  const int l15 = lane & 15, quad = lane >> 4;

  int wrowi[6];
#pragma unroll
  for (int ni = 0; ni < 6; ++ni) {
    int idx = (wave + ni * 4) * 16 + l15;
    int m = idx >> 7, dd = idx & 127;
    wrowi[ni] = m * 512 + h * 128 + dd;
  }
  float4v acc[6][2];
#pragma unroll
  for (int ni = 0; ni < 6; ++ni)
#pragma unroll
    for (int mt = 0; mt < 2; ++mt) acc[ni][mt] = (float4v){0.f, 0.f, 0.f, 0.f};

  for (int half = 0; half < 2; ++half) {
    __syncthreads();
    for (int i = tid; i < 2048; i += 256) {                // x half load
      int t = i >> 6, c4 = (i & 63) << 2;
      float4 e4 = *reinterpret_cast<const float4*>(
          g + (size_t)b * 16384 + t * 512 + half * 256 + c4);
      short4v s; s[0] = f2us(e4.x); s[1] = f2us(e4.y); s[2] = f2us(e4.z); s[3] = f2us(e4.w);
      *reinterpret_cast<short4v*>(xs2 + t * XS2_STR + c4) = s;
    }
    __syncthreads();
    for (int kl = 0; kl < 2; ++kl) {
      const int kg = half * 2 + kl;
      short8v af[2][4];
#pragma unroll
      for (int mt = 0; mt < 2; ++mt)
#pragma unroll
        for (int u = 0; u < 4; ++u)
          af[mt][u] = *reinterpret_cast<const short8v*>(
              xs2 + (mt * 16 + l15) * XS2_STR + kl * 128 + u * 32 + quad * 8);
#pragma unroll
      for (int ni = 0; ni < 6; ++ni) {
        const unsigned short* wrow = twb + (size_t)wrowi[ni] * 512 + kg * 128;
#pragma unroll
        for (int u = 0; u < 4; ++u) {
          short8v bfr = *reinterpret_cast<const short8v*>(wrow + u * 32 + quad * 8);
          acc[ni][0] = MFMA16(af[0][u], bfr, acc[ni][0], 0, 0, 0);
          acc[ni][1] = MFMA16(af[1][u], bfr, acc[ni][1], 0, 0, 0);
        }
      }
    }
  }
  // epilogue: q,k rows; V transposed
#pragma unroll
  for (int ni = 0; ni < 6; ++ni) {
    int idx = (wave + ni * 4) * 16 + l15;
    int m = idx >> 7, dd = idx & 127;
    float bj = Bv[wrowi[ni]];
    if (m < 2) {
      unsigned short* dst = (m == 0) ? qs : ks;
#pragma unroll
      for (int r = 0; r < 4; ++r) {
        int t0 = quad * 4 + r;
        dst[t0 * 136 + dd] = f2us(acc[ni][0][r] + bj);
        dst[(t0 + 16) * 136 + dd] = f2us(acc[ni][1][r] + bj);
      }
    } else {
      short4v s0, s1;
#pragma unroll
      for (int r = 0; r < 4; ++r) { s0[r] = f2us(acc[ni][0][r] + bj); s1[r] = f2us(acc[ni][1][r] + bj); }
      *reinterpret_cast<short4v*>(vT + dd * 40 + quad * 4) = s0;
      *reinterpret_cast<short4v*>(vT + dd * 40 + 16 + quad * 4) = s1;
    }
  }
  __syncthreads();
  // ---- scores MFMA: wave -> tile (mt,nt); S = Q.K^T (M=32,N=32,K=128) ----
  {
    const float scale2 = 0.08838834764831845f;            // 1/sqrt(128)
    const int mt = wave >> 1, nt = wave & 1;
    float4v a = {0.f, 0.f, 0.f, 0.f};
#pragma unroll
    for (int kc = 0; kc < 4; ++kc) {
      short8v qf = *reinterpret_cast<const short8v*>(qs + (mt * 16 + l15) * 136 + kc * 32 + quad * 8);
      short8v kf = *reinterpret_cast<const short8v*>(ks + (nt * 16 + l15) * 136 + kc * 32 + quad * 8);
      a = MFMA16(qf, kf, a, 0, 0, 0);
    }
#pragma unroll
    for (int r = 0; r < 4; ++r)
      sc[(mt * 16 + quad * 4 + r) * 33 + nt * 16 + l15] = a[r] * scale2;
  }
  __syncthreads();
  // ---- softmax rows: 4 lanes/row, shfl-reduce; bf16 unnormalized P ----
  if (tid < 128) {
    int row = tid >> 2, seg = tid & 3;
    float* srow = sc + row * 33;
    float mx = srow[seg * 8];
#pragma unroll
    for (int c = 1; c < 8; ++c) mx = fmaxf(mx, srow[seg * 8 + c]);
    mx = fmaxf(mx, __shfl_xor(mx, 1));
    mx = fmaxf(mx, __shfl_xor(mx, 2));
    float s = 0.f;
    short8v pv;
#pragma unroll
    for (int c = 0; c < 8; ++c) {
      float e = expf(srow[seg * 8 + c] - mx);
      s += e; pv[c] = f2us(e);
    }
    *reinterpret_cast<short8v*>(pb + row * 32 + seg * 8) = pv;
    s += __shfl_xor(s, 1);
    s += __shfl_xor(s, 2);
    if (seg == 0) srow[32] = 1.f / s;
  }
  __syncthreads();
  // ---- PV MFMA: O = P.V (M=32,N=128,K=32); wave handles n-tiles 2w,2w+1 ----
  {
    short8v pf[2], vf[2];
#pragma unroll
    for (int mt = 0; mt < 2; ++mt)
      pf[mt] = *reinterpret_cast<const short8v*>(pb + (mt * 16 + l15) * 32 + quad * 8);
#pragma unroll
    for (int ntl = 0; ntl < 2; ++ntl)
      vf[ntl] = *reinterpret_cast<const short8v*>(vT + ((2 * wave + ntl) * 16 + l15) * 40 + quad * 8);
    float4v oacc[2][2];
#pragma unroll
    for (int mt = 0; mt < 2; ++mt)
#pragma unroll
      for (int ntl = 0; ntl < 2; ++ntl) {
        oacc[mt][ntl] = (float4v){0.f, 0.f, 0.f, 0.f};
        oacc[mt][ntl] = MFMA16(pf[mt], vf[ntl], oacc[mt][ntl], 0, 0, 0);
      }
#pragma unroll
    for (int mt = 0; mt < 2; ++mt)
#pragma unroll
      for (int r = 0; r < 4; ++r) {
        int q = mt * 16 + quad * 4 + r;
        float inv = sc[q * 33 + 32];
#pragma unroll
        for (int ntl = 0; ntl < 2; ++ntl)
          attn[((size_t)b * 32 + q) * 512 + h * 128 + (2 * wave + ntl) * 16 + l15] =
              oacc[mt][ntl][r] * inv;
      }
  }
}

// ---------------------------------------------------------------------------
// proj GEMM via MFMA (M=16/block, N=512, K=512) + bias + residual + LN.
// ---------------------------------------------------------------------------
__global__ __launch_bounds__(256, 2) void k_projln_mfma(
    const float* __restrict__ X, const unsigned short* __restrict__ Wb,
    const float* __restrict__ bias, const float* __restrict__ res,
    const float* __restrict__ gam, const float* __restrict__ bet,
    float* __restrict__ Y)
{
  const int row0 = blockIdx.x * 16, tid = threadIdx.x;
  __shared__ alignas(16) unsigned short xs[16 * 520];
  __shared__ float ys[16 * 516];
  for (int i = tid; i < 16 * 512; i += 256) {
    int t = i >> 9, c = i & 511;
    xs[t * 520 + c] = f2us(X[(size_t)(row0 + t) * 512 + c]);
  }
  __syncthreads();
  {
    const int lane = tid & 63, wave = tid >> 6;
    const int l15 = lane & 15, quad = lane >> 4;
    short8v af[16];
#pragma unroll
    for (int kc = 0; kc < 16; ++kc)
      af[kc] = *reinterpret_cast<const short8v*>(xs + l15 * 520 + kc * 32 + quad * 8);
    for (int ni = 0; ni < 8; ++ni) {
      int col = (wave + ni * 4) * 16 + l15;
      const unsigned short* wrow = Wb + (size_t)col * 512;
      float4v acc = {0.f,0.f,0.f,0.f};
#pragma unroll
      for (int kc = 0; kc < 16; ++kc) {
        short8v bfr = *reinterpret_cast<const short8v*>(wrow + kc * 32 + quad * 8);
        acc = MFMA16(af[kc], bfr, acc, 0, 0, 0);
      }
      float bj = bias[col];
#pragma unroll
      for (int r = 0; r < 4; ++r)
        ys[(quad * 4 + r) * 516 + col] = acc[r] + bj;
    }
  }
  __syncthreads();
  for (int i = tid; i < 16 * 512; i += 256) {
    int t = i >> 9, c = i & 511;
    ys[t * 516 + c] += res[(size_t)(row0 + t) * 512 + c];
  }
  __syncthreads();
  {
    int row = tid >> 4, l16 = tid & 15;
    const float* yr = ys + row * 516;
    float part = 0.f;
#pragma unroll
    for (int k = 0; k < 32; ++k) part += yr[l16 + 16 * k];
#pragma unroll
    for (int off = 8; off; off >>= 1) part += __shfl_xor(part, off, 16);
    float mean = part * (1.f / 512.f);
    float var = 0.f;
#pragma unroll
    for (int k = 0; k < 32; ++k) { float d = yr[l16 + 16 * k] - mean; var += d * d; }
#pragma unroll
    for (int off = 8; off; off >>= 1) var += __shfl_xor(var, off, 16);
    float rs = rsqrtf(var * (1.f / 512.f) + 1e-5f);
    for (int k = 0; k < 32; ++k) {
      int c = l16 + 16 * k;
      Y[(size_t)(row0 + row) * 512 + c] = (yr[c] - mean) * rs * gam[c] + bet[c];
    }
  }
}

// ---------------------------------------------------------------------------
// ff1 GEMM via MFMA (M=16/block, N=1024, K=512) + bias + relu -> bf16.
// ---------------------------------------------------------------------------
__global__ __launch_bounds__(256, 2) void k_ff1_mfma(
    const float* __restrict__ X, const unsigned short* __restrict__ Wb,
    const float* __restrict__ bias, unsigned short* __restrict__ Y)
{
  const int row0 = blockIdx.x * 16, tid = threadIdx.x;
  __shared__ alignas(16) unsigned short xs[16 * 520];
  for (int i = tid; i < 16 * 512; i += 256) {
    int t = i >> 9, c = i & 511;
    xs[t * 520 + c] = f2us(X[(size_t)(row0 + t) * 512 + c]);
  }
  __syncthreads();
  const int lane = tid & 63, wave = tid >> 6;
  const int l15 = lane & 15, quad = lane >> 4;
  short8v af[16];
#pragma unroll
  for (int kc = 0; kc < 16; ++kc)
    af[kc] = *reinterpret_cast<const short8v*>(xs + l15 * 520 + kc * 32 + quad * 8);
  for (int ni = 0; ni < 16; ++ni) {
    int col = (wave + ni * 4) * 16 + l15;
    const unsigned short* wrow = Wb + (size_t)col * 512;
    float4v acc = {0.f,0.f,0.f,0.f};
#pragma unroll
    for (int kc = 0; kc < 16; ++kc) {
      short8v bfr = *reinterpret_cast<const short8v*>(wrow + kc * 32 + quad * 8);
      acc = MFMA16(af[kc], bfr, acc, 0, 0, 0);
    }
    float bj = bias[col];
#pragma unroll
    for (int r = 0; r < 4; ++r)
      Y[(size_t)(row0 + quad * 4 + r) * 1024 + col] = f2us(fmaxf(acc[r] + bj, 0.f));
  }
}

// ---------------------------------------------------------------------------
// ff2 GEMM via MFMA (M=16/block, N=512, K=1024 in 2 chunks) + bias +
// residual + LN. Y fp32 overlays X bf16 in-place.
// ---------------------------------------------------------------------------
__global__ __launch_bounds__(256, 2) void k_ff2ln_mfma(
    const unsigned short* __restrict__ X, const unsigned short* __restrict__ Wb,
    const float* __restrict__ bias, const float* __restrict__ res,
    const float* __restrict__ gam, const float* __restrict__ bet,
    float* __restrict__ Y)
{
  const int row0 = blockIdx.x * 16, tid = threadIdx.x;
  __shared__ alignas(16) unsigned short xs[16 * 520];
  __shared__ float ys[16 * 516];
  const int lane = tid & 63, wave = tid >> 6;
  const int l15 = lane & 15, quad = lane >> 4;
  float4v acc[8];
#pragma unroll
  for (int ni = 0; ni < 8; ++ni) acc[ni] = (float4v){0.f,0.f,0.f,0.f};
  for (int half = 0; half < 2; ++half) {
    __syncthreads();
    for (int i = tid; i < 16 * 512; i += 256) {
      int t = i >> 9, c = i & 511;
      xs[t * 520 + c] = X[(size_t)(row0 + t) * 1024 + half * 512 + c];
    }
    __syncthreads();
    short8v af[16];
#pragma unroll
    for (int kc = 0; kc < 16; ++kc)
      af[kc] = *reinterpret_cast<const short8v*>(xs + l15 * 520 + kc * 32 + quad * 8);
#pragma unroll
    for (int ni = 0; ni < 8; ++ni) {
      int col = (wave + ni * 4) * 16 + l15;
      const unsigned short* wrow = Wb + (size_t)col * 1024 + half * 512;
#pragma unroll
      for (int kc = 0; kc < 16; ++kc) {
        short8v bfr = *reinterpret_cast<const short8v*>(wrow + kc * 32 + quad * 8);
        acc[ni] = MFMA16(af[kc], bfr, acc[ni], 0, 0, 0);
      }
    }
  }
  __syncthreads();
  for (int ni = 0; ni < 8; ++ni) {
    int col = (wave + ni * 4) * 16 + l15;
    float bj = bias[col];
#pragma unroll
    for (int r = 0; r < 4; ++r)
      ys[(quad * 4 + r) * 516 + col] = acc[ni][r] + bj;
  }
  __syncthreads();
  for (int i = tid; i < 16 * 512; i += 256) {
    int t = i >> 9, c = i & 511;
    ys[t * 516 + c] += res[(size_t)(row0 + t) * 512 + c];
  }
  __syncthreads();
  {
    int row = tid >> 4, l16 = tid & 15;
    const float* yr = ys + row * 516;
    float part = 0.f;
#pragma unroll
    for (int k = 0; k < 32; ++k) part += yr[l16 + 16 * k];
#pragma unroll
    for (int off = 8; off; off >>= 1) part += __shfl_xor(part, off, 16);
    float mean = part * (1.f / 512.f);
    float var = 0.f;
#pragma unroll
    for (int k = 0; k < 32; ++k) { float d = yr[l16 + 16 * k] - mean; var += d * d; }
#pragma unroll
    for (int off = 8; off; off >>= 1) var += __shfl_xor(var, off, 16);
    float rs = rsqrtf(var * (1.f / 512.f) + 1e-5f);
    for (int k = 0; k < 32; ++k) {
      int c = l16 + 16 * k;
      Y[(size_t)(row0 + row) * 512 + c] = (yr[c] - mean) * rs * gam[c] + bet[c];
    }
  }
}

// ---------------------------------------------------------------------------
// Final: mean-pool, temporal MLP, concat, classifier, LN, relu -> fp32
// ---------------------------------------------------------------------------
__global__ __launch_bounds__(256) void k_final(
    const float* __restrict__ g2,
    const float* __restrict__ db, const float* __restrict__ dsl,
    const float* __restrict__ te1_w, const float* __restrict__ te1_b,
    const float* __restrict__ l1g, const float* __restrict__ l1b,
    const float* __restrict__ te2_w, const float* __restrict__ te2_b,
    const float* __restrict__ l2g, const float* __restrict__ l2b,
    const float* __restrict__ c_w, const float* __restrict__ c_b,
    const float* __restrict__ clg, const float* __restrict__ clb,
    float* __restrict__ out)
{
  const int b = blockIdx.x, tid = threadIdx.x;
  __shared__ float cat[640];
  __shared__ float t1[64];
  __shared__ float t2[128];
  __shared__ float pre[256];
  __shared__ float red[256];
  __shared__ float st[2];
  for (int i = tid; i < 512; i += 256) {
    float acc = 0.f;
#pragma unroll
    for (int t = 0; t < 32; ++t) acc += g2[((size_t)b * 32 + t) * 512 + i];
    cat[i] = acc * (1.f / 32.f);
  }
  if (tid == 0) {
    float s = 0.f;
    for (int i = 0; i < 31; ++i) s += db[b * 31 + i];
    st[0] = s / 31.f;
    st[1] = dsl[b];
  }
  __syncthreads();
  const float f0 = st[0], f1v = st[1];
  if (tid < 64)
    t1[tid] = f0 * te1_w[tid * 2] + f1v * te1_w[tid * 2 + 1] + te1_b[tid];
  __syncthreads();
  if (tid == 0) {
    float m = 0.f; for (int i = 0; i < 64; ++i) m += t1[i]; m *= (1.f / 64.f);
    float v = 0.f; for (int i = 0; i < 64; ++i) { float d = t1[i] - m; v += d * d; }
    st[0] = m; st[1] = rsqrtf(v * (1.f / 64.f) + 1e-5f);
  }
  __syncthreads();
  if (tid < 64) {
    float v = (t1[tid] - st[0]) * st[1] * l1g[tid] + l1b[tid];
    t1[tid] = fmaxf(v, 0.f);
  }
  __syncthreads();
  if (tid < 128)
    t2[tid] = dot_ff(t1, te2_w + (size_t)tid * 64, 64) + te2_b[tid];
  __syncthreads();
  if (tid == 0) {
    float m = 0.f; for (int i = 0; i < 128; ++i) m += t2[i]; m *= (1.f / 128.f);
    float v = 0.f; for (int i = 0; i < 128; ++i) { float d = t2[i] - m; v += d * d; }
    st[0] = m; st[1] = rsqrtf(v * (1.f / 128.f) + 1e-5f);
  }
  __syncthreads();
  if (tid < 128) {
    float v = (t2[tid] - st[0]) * st[1] * l2g[tid] + l2b[tid];
    cat[512 + tid] = fmaxf(v, 0.f);
  }
  __syncthreads();
  pre[tid] = dot_ff(cat, c_w + (size_t)tid * 640, 640) + c_b[tid];
  red[tid] = pre[tid];
  __syncthreads();
  for (int s = 128; s > 0; s >>= 1) { if (tid < s) red[tid] += red[tid + s]; __syncthreads(); }
  const float m = red[0] * (1.f / 256.f);
  __syncthreads();
  const float d = pre[tid] - m;
  red[tid] = d * d;
  __syncthreads();
  for (int s = 128; s > 0; s >>= 1) { if (tid < s) red[tid] += red[tid + s]; __syncthreads(); }
  const float rs = rsqrtf(red[0] * (1.f / 256.f) + 1e-5f);
  float v = d * rs * clg[tid] + clb[tid];
  out[(size_t)b * 256 + tid] = fmaxf(v, 0.f);
}

// ---------------------------------------------------------------------------
extern "C" void kernel_launch(void* const* d_in, const int* in_sizes, int n_in,
                              void* d_out, int out_size, void* d_ws, size_t ws_size,
                              hipStream_t stream) {
  (void)in_sizes; (void)n_in; (void)out_size; (void)ws_size;
  const int*   oh     = (const int*)  d_in[0];
  const float* db     = (const float*)d_in[1];
  const float* dsl    = (const float*)d_in[2];
  const float* emb    = (const float*)d_in[3];
  const float* a_in_w = (const float*)d_in[4];
  const float* a_in_b = (const float*)d_in[5];
  const float* a_out_w= (const float*)d_in[6];
  const float* a_out_b= (const float*)d_in[7];
  const float* wih_f  = (const float*)d_in[8];
  const float* whh_f  = (const float*)d_in[9];
  const float* bih_f  = (const float*)d_in[10];
  const float* bhh_f  = (const float*)d_in[11];
  const float* wih_b  = (const float*)d_in[12];
  const float* whh_b  = (const float*)d_in[13];
  const float* bih_b  = (const float*)d_in[14];
  const float* bhh_b  = (const float*)d_in[15];
  const float* t_in_w = (const float*)d_in[16];
  const float* t_in_b = (const float*)d_in[17];
  const float* t_out_w= (const float*)d_in[18];
  const float* t_out_b= (const float*)d_in[19];
  const float* t_ln1g = (const float*)d_in[20];
  const float* t_ln1b = (const float*)d_in[21];
  const float* t_ff1w = (const float*)d_in[22];
  const float* t_ff1b = (const float*)d_in[23];
  const float* t_ff2w = (const float*)d_in[24];
  const float* t_ff2b = (const float*)d_in[25];
  const float* t_ln2g = (const float*)d_in[26];
  const float* t_ln2b = (const float*)d_in[27];
  const float* te1_w  = (const float*)d_in[28];
  const float* te1_b  = (const float*)d_in[29];
  const float* tl1g   = (const float*)d_in[30];
  const float* tl1b   = (const float*)d_in[31];
  const float* te2_w  = (const float*)d_in[32];
  const float* te2_b  = (const float*)d_in[33];
  const float* tl2g   = (const float*)d_in[34];
  const float* tl2b   = (const float*)d_in[35];
  const float* c_w    = (const float*)d_in[36];
  const float* c_b    = (const float*)d_in[37];
  const float* clng   = (const float*)d_in[38];
  const float* clnb   = (const float*)d_in[39];

  float* ws = (float*)d_ws;
  // Workspace (float slots), max index 17,391,616 (~69.6 MB):
  //   A [0,        1048576): oe [8192,128] fp32
  //   B [1048576,  5242880): g fp32 -> f1 bf16 (over dead g) -> g2 fp32
  //   C [5242880,  9437184): attn fp32; g1 = LN out in-place
  //   D [9437184,  9633792): whhb bf16 [2][768][256]
  //   D2[9633792,  9732096): wihb bf16 [2][768][128]
  //   D3[9732096,  9740288): awb2 bf16 [128*128]
  //   E [10027008,10051584): awb bf16 [384*128]
  //   F [10051584,10444800): twb bf16 [1536*512]
  //   G [10444800,10575872): pwb bf16 [512*512]
  //   G2[10575872,10838016): f1wb bf16 [1024*512]
  //   G3[10838016,11100160): f2wb bf16 [512*1024]
  //   H [11100160,17391616): gi bf16 [8192*1536]
  float* oe   = ws;
  float* g    = ws + 1048576;
  float* attn = ws + 5242880;
  float* g1   = attn;                                   // in-place
  unsigned short* f1 = (unsigned short*)(ws + 1048576); // over dead g
  float* g2   = ws + 1048576;                           // in-place over f1
  unsigned short* whhb = (unsigned short*)(ws + 9437184);
  unsigned short* wihb = (unsigned short*)(ws + 9633792);
  unsigned short* awb2 = (unsigned short*)(ws + 9732096);
  unsigned short* awb  = (unsigned short*)(ws + 10027008);
  unsigned short* twb  = (unsigned short*)(ws + 10051584);
  unsigned short* pwb  = (unsigned short*)(ws + 10444800);
  unsigned short* f1wb = (unsigned short*)(ws + 10575872);
  unsigned short* f2wb = (unsigned short*)(ws + 10838016);
  unsigned short* gi   = (unsigned short*)(ws + 11100160);

  k_canary<<<256, 256, 0, stream>>>((float*)d_out);
  k_cvt<<<3072, 256, 0, stream>>>(a_in_w, t_in_w, t_out_w, t_ff1w, t_ff2w, a_out_w,
                                  awb, twb, pwb, f1wb, f2wb, awb2);
  k_gru_wb<<<1536, 256, 0, stream>>>(wih_f, whh_f, wih_b, whh_b, whhb, wihb);
  k_order_attn<<<8192, 256, 0, stream>>>(oh, emb, awb, a_in_b, awb2, a_out_b, oe);
  k_gru_gi<<<256, 256, 0, stream>>>(oe, wihb, gi);
  k_gru_rec<<<dim3(128, 2), 512, 0, stream>>>(gi, whhb, bih_f, bhh_f, bih_b, bhh_b, g);
  k_mha2f<<<dim3(256, 4), 256, 0, stream>>>(g, twb, t_in_b, attn);
  k_projln_mfma<<<512, 256, 0, stream>>>(attn, pwb, t_out_b, g, t_ln1g, t_ln1b, g1);
  k_ff1_mfma<<<512, 256, 0, stream>>>(g1, f1wb, t_ff1b, f1);
  k_ff2ln_mfma<<<512, 256, 0, stream>>>(f1, f2wb, t_ff2b, g1, t_ln2g, t_ln2b, g2);
  k_final<<<256, 256, 0, stream>>>(g2, db, dsl, te1_w, te1_b, tl1g, tl1b,
                                   te2_w, te2_b, tl2g, tl2b, c_w, c_b, clng, clnb,
                                   (float*)d_out);
}